// Round 1
// baseline (59733.582 us; speedup 1.0000x reference)
//
#include <hip/hip_runtime.h>
#include <math.h>

#define B_    64
#define T_    256
#define C_    16
#define DW    256
#define DC    64
#define HH    512
#define D0    320
#define D12   1024
#define G4    2048
#define NSEQ  16384

__device__ __forceinline__ float sigf(float x)  { return 1.0f/(1.0f + __expf(-x)); }
__device__ __forceinline__ float tanhf_(float x){ return 1.0f - 2.0f/(1.0f + __expf(2.0f*x)); }

// ---------------- weight permutes ----------------
// wihP[g4][k], g4 = u*4+q, src row = q*HH+u
__global__ void __launch_bounds__(256) k_perm_ih(const float* __restrict__ src,
                                                 float* __restrict__ dst, int D) {
  size_t total = (size_t)G4 * (size_t)D;
  for (size_t i = (size_t)blockIdx.x*256 + threadIdx.x; i < total; i += (size_t)gridDim.x*256) {
    int g4 = (int)(i / (size_t)D);
    int k  = (int)(i - (size_t)g4*(size_t)D);
    int u = g4 >> 2, q = g4 & 3;
    dst[i] = src[(size_t)(q*HH + u)*D + k];
  }
}

// whhP[u*2048 + k*4 + q] = src[(q*512+u)*512 + k]
__global__ void __launch_bounds__(256) k_perm_hh(const float* __restrict__ src,
                                                 float* __restrict__ dst) {
  int total = G4*HH;
  for (int i = blockIdx.x*256 + threadIdx.x; i < total; i += gridDim.x*256) {
    int u = i >> 11, rem = i & 2047, k = rem >> 2, q = rem & 3;
    dst[i] = src[(size_t)(q*HH + u)*HH + k];
  }
}

// whhc[k*256 + u*4 + q] = src[(q*64+u)*64 + k]
__global__ void __launch_bounds__(256) k_perm_hh_char(const float* __restrict__ src,
                                                      float* __restrict__ dst) {
  int i = blockIdx.x*256 + threadIdx.x;
  if (i < 64*256) {
    int k = i >> 8, rem = i & 255, u = rem >> 2, q = rem & 3;
    dst[i] = src[(q*64 + u)*64 + k];
  }
}

__global__ void __launch_bounds__(256) k_perm_b(const float* __restrict__ src,
                                                float* __restrict__ dst) {
  int i = blockIdx.x*256 + threadIdx.x;
  if (i < G4) { int u = i >> 2, q = i & 3; dst[i] = src[q*HH + u]; }
}

// ---------------- embeddings ----------------
__global__ void __launch_bounds__(256) k_word_emb(const int* __restrict__ words,
                                                  const float* __restrict__ wl,
                                                  float* __restrict__ x) {
  int tok = blockIdx.x;            // n*256 + w
  int row = words[tok];
  int tid = threadIdx.x;
  float e = wl[(size_t)row*DW + tid];
  float ss = e*e;
  #pragma unroll
  for (int o = 32; o; o >>= 1) ss += __shfl_xor(ss, o, 64);
  __shared__ float wsum[4];
  __shared__ float sc;
  int lane = tid & 63, wv = tid >> 6;
  if (lane == 0) wsum[wv] = ss;
  __syncthreads();
  if (tid == 0) {
    float s2 = wsum[0] + wsum[1] + wsum[2] + wsum[3];
    float nn = sqrtf(s2);
    sc = (nn > 1.0f) ? 1.0f/nn : 1.0f;
  }
  __syncthreads();
  x[(size_t)tok*D0 + tid] = e*sc;
}

// char pregate table: preT[v][u*4+q] = b[q*64+u] + renorm(cl_emb[v]) . wih[q*64+u]
__global__ void __launch_bounds__(256) k_pret(const float* __restrict__ cl_emb,
                                              const float* __restrict__ wih,
                                              const float* __restrict__ b,
                                              float* __restrict__ preT) {
  int r = blockIdx.x;
  int tid = threadIdx.x;
  __shared__ float e[64];
  if (tid < 64) e[tid] = cl_emb[r*64 + tid];
  __syncthreads();
  float ss = 0.f;
  #pragma unroll 8
  for (int k = 0; k < 64; ++k) ss += e[k]*e[k];
  float nn = sqrtf(ss);
  float scl = (nn > 1.0f) ? 1.0f/nn : 1.0f;
  int u = tid >> 2, q = tid & 3;
  const float* wrow = wih + (q*64 + u)*64;
  float acc = 0.f;
  #pragma unroll 8
  for (int k = 0; k < 64; ++k) acc += e[k]*wrow[k];
  preT[r*256 + tid] = b[q*64 + u] + scl*acc;
}

// ---------------- char LSTM: 256 blocks x 64 sequences, h in LDS ----------------
__global__ void __launch_bounds__(256) k_char(const int* __restrict__ chars,
                                              const float* __restrict__ preT,
                                              const float* __restrict__ whhc,
                                              float* __restrict__ x) {
  __shared__ float hb[2][64*68];   // [phase][unit][seq], stride 68 breaks bank conflicts
  int tid = threadIdx.x;
  int u = tid & 63, sg = tid >> 6;
  int sbase = blockIdx.x*64 + sg*16;
  float c[16];
  float4 acc[16];
  for (int t = 0; t < C_; ++t) {
    #pragma unroll
    for (int i = 0; i < 16; ++i) {
      int ch = chars[(sbase + i)*C_ + t];
      acc[i] = *(const float4*)(preT + ch*256 + (u << 2));
    }
    if (t > 0) {
      const float* hp = hb[(t - 1) & 1] + (sg << 4);
      #pragma unroll 2
      for (int k = 0; k < 64; ++k) {
        float4 w = *(const float4*)(whhc + (k << 8) + (u << 2));
        const float* hr = hp + k*68;
        float4 h0 = *(const float4*)(hr + 0);
        float4 h1 = *(const float4*)(hr + 4);
        float4 h2 = *(const float4*)(hr + 8);
        float4 h3 = *(const float4*)(hr + 12);
        float hv[16] = {h0.x,h0.y,h0.z,h0.w, h1.x,h1.y,h1.z,h1.w,
                        h2.x,h2.y,h2.z,h2.w, h3.x,h3.y,h3.z,h3.w};
        #pragma unroll
        for (int i = 0; i < 16; ++i) {
          acc[i].x += w.x*hv[i]; acc[i].y += w.y*hv[i];
          acc[i].z += w.z*hv[i]; acc[i].w += w.w*hv[i];
        }
      }
    }
    float* hw = hb[t & 1];
    #pragma unroll
    for (int i = 0; i < 16; ++i) {
      float ig = sigf(acc[i].x), fg = sigf(acc[i].y);
      float gg = tanhf_(acc[i].z), og = sigf(acc[i].w);
      float cc = (t == 0) ? (ig*gg) : (fg*c[i] + ig*gg);
      c[i] = cc;
      float hh = og*tanhf_(cc);
      hw[u*68 + (sg << 4) + i] = hh;
      if (t == C_-1) x[(size_t)(sbase + i)*D0 + DW + u] = hh;
    }
    __syncthreads();
  }
}

// ---------------- pregate GEMM: preg[dir][s][n][g4] = in . wihP^T + bP ----------------
__global__ void __launch_bounds__(256) k_gemm_pre(const float* __restrict__ in,
    const float* __restrict__ wihPf, const float* __restrict__ wihPb,
    const float* __restrict__ bPf,   const float* __restrict__ bPb,
    float* __restrict__ preg, int D, int t0, int TC) {
  int dir = blockIdx.z;
  const float* wihP = dir ? wihPb : wihPf;
  const float* bP   = dir ? bPb   : bPf;
  int mt = blockIdx.x, nt = blockIdx.y;
  __shared__ float As[16][132];
  __shared__ float Bs[16][132];
  int tid = threadIdx.x;
  int tx = tid & 15, ty = tid >> 4;
  float acc[8][8];
  #pragma unroll
  for (int a = 0; a < 8; ++a)
    #pragma unroll
    for (int bq = 0; bq < 8; ++bq) acc[a][bq] = 0.f;

  for (int k0 = 0; k0 < D; k0 += 16) {
    #pragma unroll
    for (int it = 0; it < 2; ++it) {
      int j = tid + it*256;              // 0..511
      int mloc = j >> 2, kq = (j & 3) << 2;
      int r = mt*128 + mloc;
      int s = r >> 6, n = r & 63;
      int tt = dir ? (T_ - 1 - (t0 + s)) : (t0 + s);
      float4 v = *(const float4*)(in + ((size_t)n*T_ + tt)*D + k0 + kq);
      As[kq+0][mloc] = v.x; As[kq+1][mloc] = v.y; As[kq+2][mloc] = v.z; As[kq+3][mloc] = v.w;
      int g = nt*128 + mloc;
      float4 w = *(const float4*)(wihP + (size_t)g*D + k0 + kq);
      Bs[kq+0][mloc] = w.x; Bs[kq+1][mloc] = w.y; Bs[kq+2][mloc] = w.z; Bs[kq+3][mloc] = w.w;
    }
    __syncthreads();
    #pragma unroll
    for (int k = 0; k < 16; ++k) {
      float4 a0 = *(const float4*)&As[k][tx*8];
      float4 a1 = *(const float4*)&As[k][tx*8 + 4];
      float4 b0 = *(const float4*)&Bs[k][ty*8];
      float4 b1 = *(const float4*)&Bs[k][ty*8 + 4];
      float av[8] = {a0.x,a0.y,a0.z,a0.w, a1.x,a1.y,a1.z,a1.w};
      float bv[8] = {b0.x,b0.y,b0.z,b0.w, b1.x,b1.y,b1.z,b1.w};
      #pragma unroll
      for (int me = 0; me < 8; ++me)
        #pragma unroll
        for (int ne = 0; ne < 8; ++ne)
          acc[me][ne] += av[me]*bv[ne];
    }
    __syncthreads();
  }
  int gbase = nt*128 + ty*8;
  float bias[8];
  #pragma unroll
  for (int ne = 0; ne < 8; ++ne) bias[ne] = bP[gbase + ne];
  #pragma unroll
  for (int me = 0; me < 8; ++me) {
    int r = mt*128 + tx*8 + me;
    int s = r >> 6, n = r & 63;
    float* op = preg + (((size_t)dir*TC + s)*64 + n)*2048 + gbase;
    float4 o0, o1;
    o0.x = acc[me][0] + bias[0]; o0.y = acc[me][1] + bias[1];
    o0.z = acc[me][2] + bias[2]; o0.w = acc[me][3] + bias[3];
    o1.x = acc[me][4] + bias[4]; o1.y = acc[me][5] + bias[5];
    o1.z = acc[me][6] + bias[6]; o1.w = acc[me][7] + bias[7];
    *(float4*)op = o0;
    *(float4*)(op + 4) = o1;
  }
}

// ---------------- main recurrence: 256 blocks, grid barrier per step ----------------
__global__ void __launch_bounds__(256) k_rec(const float* __restrict__ preg,
    const float* __restrict__ whhPf, const float* __restrict__ whhPb,
    float* __restrict__ h_out, float* __restrict__ hTst, float* __restrict__ cst,
    int* __restrict__ counter, int t0, int TC) {
  int dir  = blockIdx.x >> 7;
  int ublk = blockIdx.x & 127;
  const float* whhP = dir ? whhPb : whhPf;
  int tid = threadIdx.x;
  int n = tid & 63;
  int uu = __builtin_amdgcn_readfirstlane(tid >> 6);   // wave-uniform -> s_load for weights
  int u = (ublk << 2) + uu;
  const float* wbase = whhP + ((size_t)u << 11);       // [k][4] slice for this unit
  float c = (t0 == 0) ? 0.f : cst[(dir << 15) + (u << 6) + n];
  for (int s = 0; s < TC; ++s) {
    int t = t0 + s;
    int tt = dir ? (T_ - 1 - t) : t;
    float4 acc = *(const float4*)(preg + (((size_t)dir*TC + s)*64 + n)*2048 + (u << 2));
    if (t > 0) {
      const float* hp = hTst + (size_t)((dir << 1) | ((t - 1) & 1))*(512*64) + n;
      #pragma unroll 8
      for (int k = 0; k < 512; ++k) {
        float4 wv = *(const float4*)(wbase + (k << 2));
        float hv = hp[k << 6];
        acc.x += wv.x*hv; acc.y += wv.y*hv; acc.z += wv.z*hv; acc.w += wv.w*hv;
      }
    }
    float ig = sigf(acc.x), fg = sigf(acc.y), gg = tanhf_(acc.z), og = sigf(acc.w);
    c = fg*c + ig*gg;
    float h = og*tanhf_(c);
    h_out[((size_t)n*T_ + tt)*D12 + (dir << 9) + u] = h;
    hTst[(size_t)((dir << 1) | (t & 1))*(512*64) + (u << 6) + n] = h;
    // ---- grid barrier (all 256 blocks trivially co-resident: 256 thr, no LDS) ----
    __syncthreads();
    __threadfence();
    if (tid == 0) {
      atomicAdd(counter, 1);
      int target = (s + 1) << 8;   // 256 blocks
      while (__hip_atomic_load(counter, __ATOMIC_RELAXED, __HIP_MEMORY_SCOPE_AGENT) < target)
        __builtin_amdgcn_s_sleep(2);
    }
    __syncthreads();
    __threadfence();
  }
  cst[(dir << 15) + (u << 6) + n] = c;
}

// ---------------- classifier ----------------
__global__ void __launch_bounds__(256) k_cls(const float* __restrict__ h,
                                             const float* __restrict__ Wc,
                                             const float* __restrict__ bc,
                                             float* __restrict__ out) {
  int n = blockIdx.x, tid = threadIdx.x;
  float p0 = 0.f, p1 = 0.f, p2 = 0.f;
  for (int j = tid; j < 1024; j += 256) {
    int t = (j < 512) ? (T_ - 1) : 0;
    float f = h[((size_t)n*T_ + t)*D12 + j];
    p0 += f*Wc[j]; p1 += f*Wc[1024 + j]; p2 += f*Wc[2048 + j];
  }
  #pragma unroll
  for (int o = 32; o; o >>= 1) {
    p0 += __shfl_xor(p0, o, 64);
    p1 += __shfl_xor(p1, o, 64);
    p2 += __shfl_xor(p2, o, 64);
  }
  __shared__ float red[4][3];
  int lane = tid & 63, wv = tid >> 6;
  if (lane == 0) { red[wv][0] = p0; red[wv][1] = p1; red[wv][2] = p2; }
  __syncthreads();
  if (tid < 3)
    out[n*3 + tid] = red[0][tid] + red[1][tid] + red[2][tid] + red[3][tid] + bc[tid];
}

extern "C" void kernel_launch(void* const* d_in, const int* in_sizes, int n_in,
                              void* d_out, int out_size, void* d_ws, size_t ws_size,
                              hipStream_t stream) {
  (void)in_sizes; (void)n_in; (void)out_size;
  const int*   words  = (const int*)d_in[0];
  const int*   chars  = (const int*)d_in[1];
  const float* wl_emb = (const float*)d_in[2];
  const float* cl_emb = (const float*)d_in[3];
  const float* c_wih  = (const float*)d_in[4];
  const float* c_whh  = (const float*)d_in[5];
  const float* c_b    = (const float*)d_in[6];
  const float* WIH[3][2] = {
    { (const float*)d_in[7],  (const float*)d_in[10] },
    { (const float*)d_in[13], (const float*)d_in[16] },
    { (const float*)d_in[13] + (size_t)2048*1024, (const float*)d_in[16] + (size_t)2048*1024 } };
  const float* WHH[3][2] = {
    { (const float*)d_in[8],  (const float*)d_in[11] },
    { (const float*)d_in[14], (const float*)d_in[17] },
    { (const float*)d_in[14] + (size_t)2048*512, (const float*)d_in[17] + (size_t)2048*512 } };
  const float* BB[3][2] = {
    { (const float*)d_in[9],  (const float*)d_in[12] },
    { (const float*)d_in[15], (const float*)d_in[18] },
    { (const float*)d_in[15] + 2048, (const float*)d_in[18] + 2048 } };
  const float* Wc = (const float*)d_in[19];
  const float* bc = (const float*)d_in[20];

  // -------- workspace carve --------
  float* wsp = (float*)d_ws;
  size_t off = 0;
  auto carve = [&](size_t nf) { float* p = wsp + off; off += (nf + 63) & ~(size_t)63; return p; };
  float* x    = carve((size_t)NSEQ*D0);
  float* hA   = carve((size_t)NSEQ*D12);
  float* hB   = carve((size_t)NSEQ*D12);
  float* preT = carve(100*256);
  float* whhc = carve(64*256);
  float* wihP[3][2]; float* whhP[3][2]; float* bP[3][2];
  for (int l = 0; l < 3; ++l)
    for (int d = 0; d < 2; ++d) {
      wihP[l][d] = carve((size_t)2048 * (l ? 1024 : 320));
      whhP[l][d] = carve((size_t)2048*512);
      bP[l][d]   = carve(2048);
    }
  float* hTst = carve((size_t)2*2*512*64);
  float* cst  = carve((size_t)2*64*512);
  int* counter = (int*)carve(64);
  size_t wsFloats = ws_size / 4;
  int TC = 64;
  while (TC > 16 && off + (size_t)2*TC*64*2048 > wsFloats) TC >>= 1;
  float* preg = carve((size_t)2*TC*64*2048);
  if (off > wsFloats) return;   // insufficient workspace -> visible validation failure

  // -------- weight permutes --------
  for (int l = 0; l < 3; ++l)
    for (int d = 0; d < 2; ++d) {
      int D = l ? D12 : D0;
      k_perm_ih<<<512, 256, 0, stream>>>(WIH[l][d], wihP[l][d], D);
      k_perm_hh<<<512, 256, 0, stream>>>(WHH[l][d], whhP[l][d]);
      k_perm_b<<<8, 256, 0, stream>>>(BB[l][d], bP[l][d]);
    }
  k_perm_hh_char<<<64, 256, 0, stream>>>(c_whh, whhc);

  // -------- embeddings + char LSTM --------
  k_pret<<<100, 256, 0, stream>>>(cl_emb, c_wih, c_b, preT);
  k_word_emb<<<NSEQ, 256, 0, stream>>>(words, wl_emb, x);
  k_char<<<256, 256, 0, stream>>>(chars, preT, whhc, x);

  // -------- 3 stacked BiLSTM layers --------
  for (int l = 0; l < 3; ++l) {
    const float* in = (l == 0) ? x : ((l == 1) ? hA : hB);
    float* ho = (l == 1) ? hB : hA;
    int D = l ? D12 : D0;
    for (int t0 = 0; t0 < T_; t0 += TC) {
      k_gemm_pre<<<dim3(TC/2, 16, 2), 256, 0, stream>>>(in, wihP[l][0], wihP[l][1],
                                                        bP[l][0], bP[l][1], preg, D, t0, TC);
      hipMemsetAsync(counter, 0, 4, stream);
      k_rec<<<256, 256, 0, stream>>>(preg, whhP[l][0], whhP[l][1], ho, hTst, cst,
                                     counter, t0, TC);
    }
  }

  // -------- classifier --------
  k_cls<<<B_, 256, 0, stream>>>(hA, Wc, bc, (float*)d_out);
}

// Round 2
// 27687.747 us; speedup vs baseline: 2.1574x; 2.1574x over previous
//
#include <hip/hip_runtime.h>
#include <math.h>

#define T_    256
#define C_    16
#define LDA   72   // ushort row stride in GEMM LDS tiles (144B: 16B-aligned, conflict-light)

typedef float  f32x4v __attribute__((ext_vector_type(4)));
typedef __bf16 bf16x8 __attribute__((ext_vector_type(8)));
typedef short  short8 __attribute__((ext_vector_type(8)));

__device__ __forceinline__ float sigf(float x)  { return 1.0f/(1.0f + __expf(-x)); }
__device__ __forceinline__ float tanhf_(float x){ return 1.0f - 2.0f/(1.0f + __expf(2.0f*x)); }

__device__ __forceinline__ ushort bfh(float x){
  uint u = __float_as_uint(x);
  return (ushort)((u + 0x7FFFu + ((u >> 16) & 1u)) >> 16);
}
__device__ __forceinline__ float bf2f(ushort h){ return __uint_as_float(((uint)h) << 16); }
__device__ __forceinline__ void bsplit(float x, ushort& h, ushort& l){
  h = bfh(x); l = bfh(x - bf2f(h));
}

// ---------- weight convert+permute: Wh/Wl[g4][k], g4=u*4+q <- src[(q*512+u)][k] ----------
__global__ void __launch_bounds__(256) k_cvt_w(const float* __restrict__ src,
                                               ushort* __restrict__ Wh,
                                               ushort* __restrict__ Wl, int D) {
  int D4 = D >> 2;
  int total4 = 2048 * D4;
  int i = blockIdx.x * 256 + threadIdx.x;
  if (i >= total4) return;
  int g4 = i / D4, k4 = i - g4 * D4;
  int u = g4 >> 2, q = g4 & 3;
  float4 v = *(const float4*)(src + ((size_t)(q * 512 + u)) * D + (k4 << 2));
  ushort4 hh, ll;
  bsplit(v.x, hh.x, ll.x); bsplit(v.y, hh.y, ll.y);
  bsplit(v.z, hh.z, ll.z); bsplit(v.w, hh.w, ll.w);
  *(ushort4*)(Wh + (size_t)g4 * D + (k4 << 2)) = hh;
  *(ushort4*)(Wl + (size_t)g4 * D + (k4 << 2)) = ll;
}

__global__ void __launch_bounds__(256) k_perm_b(const float* __restrict__ src,
                                                float* __restrict__ dst) {
  int i = blockIdx.x * 256 + threadIdx.x;
  if (i < 2048) { int u = i >> 2, q = i & 3; dst[i] = src[q * 512 + u]; }
}

// whhc[k*256 + u*4 + q] = src[(q*64+u)*64 + k]
__global__ void __launch_bounds__(256) k_perm_hh_char(const float* __restrict__ src,
                                                      float* __restrict__ dst) {
  int i = blockIdx.x * 256 + threadIdx.x;
  if (i < 64 * 256) {
    int k = i >> 8, rem = i & 255, u = rem >> 2, q = rem & 3;
    dst[i] = src[(q * 64 + u) * 64 + k];
  }
}

// ---------- embeddings ----------
__global__ void __launch_bounds__(256) k_word_emb(const int* __restrict__ words,
                                                  const float* __restrict__ wl,
                                                  ushort* __restrict__ Xh,
                                                  ushort* __restrict__ Xl) {
  int tok = blockIdx.x;
  int row = words[tok];
  int tid = threadIdx.x;
  float e = wl[(size_t)row * 256 + tid];
  float ss = e * e;
  #pragma unroll
  for (int o = 32; o; o >>= 1) ss += __shfl_xor(ss, o, 64);
  __shared__ float wsum[4];
  __shared__ float sc;
  int lane = tid & 63, wv = tid >> 6;
  if (lane == 0) wsum[wv] = ss;
  __syncthreads();
  if (tid == 0) {
    float s2 = wsum[0] + wsum[1] + wsum[2] + wsum[3];
    float nn = sqrtf(s2);
    sc = (nn > 1.0f) ? 1.0f / nn : 1.0f;
  }
  __syncthreads();
  ushort hh, ll; bsplit(e * sc, hh, ll);
  Xh[(size_t)tok * 320 + tid] = hh;
  Xl[(size_t)tok * 320 + tid] = ll;
}

// char pregate table: preT[v][u*4+q]
__global__ void __launch_bounds__(256) k_pret(const float* __restrict__ cl_emb,
                                              const float* __restrict__ wih,
                                              const float* __restrict__ b,
                                              float* __restrict__ preT) {
  int r = blockIdx.x;
  int tid = threadIdx.x;
  __shared__ float e[64];
  if (tid < 64) e[tid] = cl_emb[r * 64 + tid];
  __syncthreads();
  float ss = 0.f;
  #pragma unroll 8
  for (int k = 0; k < 64; ++k) ss += e[k] * e[k];
  float nn = sqrtf(ss);
  float scl = (nn > 1.0f) ? 1.0f / nn : 1.0f;
  int u = tid >> 2, q = tid & 3;
  const float* wrow = wih + (q * 64 + u) * 64;
  float acc = 0.f;
  #pragma unroll 8
  for (int k = 0; k < 64; ++k) acc += e[k] * wrow[k];
  preT[r * 256 + tid] = b[q * 64 + u] + scl * acc;
}

// ---------- char LSTM ----------
__global__ void __launch_bounds__(256) k_char(const int* __restrict__ chars,
                                              const float* __restrict__ preT,
                                              const float* __restrict__ whhc,
                                              ushort* __restrict__ Xh,
                                              ushort* __restrict__ Xl) {
  __shared__ float hb[2][64 * 68];
  int tid = threadIdx.x;
  int u = tid & 63, sg = tid >> 6;
  int sbase = blockIdx.x * 64 + sg * 16;
  float c[16];
  float4 acc[16];
  for (int t = 0; t < C_; ++t) {
    #pragma unroll
    for (int i = 0; i < 16; ++i) {
      int ch = chars[(sbase + i) * C_ + t];
      acc[i] = *(const float4*)(preT + ch * 256 + (u << 2));
    }
    if (t > 0) {
      const float* hp = hb[(t - 1) & 1] + (sg << 4);
      #pragma unroll 2
      for (int k = 0; k < 64; ++k) {
        float4 w = *(const float4*)(whhc + (k << 8) + (u << 2));
        const float* hr = hp + k * 68;
        float4 h0 = *(const float4*)(hr + 0);
        float4 h1 = *(const float4*)(hr + 4);
        float4 h2 = *(const float4*)(hr + 8);
        float4 h3 = *(const float4*)(hr + 12);
        float hv[16] = {h0.x,h0.y,h0.z,h0.w, h1.x,h1.y,h1.z,h1.w,
                        h2.x,h2.y,h2.z,h2.w, h3.x,h3.y,h3.z,h3.w};
        #pragma unroll
        for (int i = 0; i < 16; ++i) {
          acc[i].x += w.x*hv[i]; acc[i].y += w.y*hv[i];
          acc[i].z += w.z*hv[i]; acc[i].w += w.w*hv[i];
        }
      }
    }
    float* hw = hb[t & 1];
    #pragma unroll
    for (int i = 0; i < 16; ++i) {
      float ig = sigf(acc[i].x), fg = sigf(acc[i].y);
      float gg = tanhf_(acc[i].z), og = sigf(acc[i].w);
      float cc = (t == 0) ? (ig*gg) : (fg*c[i] + ig*gg);
      c[i] = cc;
      float hh = og * tanhf_(cc);
      hw[u*68 + (sg << 4) + i] = hh;
      if (t == C_-1) {
        ushort h_, l_; bsplit(hh, h_, l_);
        Xh[(size_t)(sbase + i) * 320 + 256 + u] = h_;
        Xl[(size_t)(sbase + i) * 320 + 256 + u] = l_;
      }
    }
    __syncthreads();
  }
}

// ---------- layer-input convert (transpose [t][n][1024] fp32 -> [n][t][1024] bf16 hi/lo) ----------
__global__ void __launch_bounds__(256) k_cvt_h(const float* __restrict__ h,
                                               ushort* __restrict__ Xh,
                                               ushort* __restrict__ Xl) {
  int row = blockIdx.x;              // t*64 + n
  int t = row >> 6, n = row & 63;
  int tid = threadIdx.x;
  float4 v = ((const float4*)(h + (size_t)row * 1024))[tid];
  size_t ob = ((size_t)n * T_ + t) * 1024 + (tid << 2);
  ushort4 hh, ll;
  bsplit(v.x, hh.x, ll.x); bsplit(v.y, hh.y, ll.y);
  bsplit(v.z, hh.z, ll.z); bsplit(v.w, hh.w, ll.w);
  *(ushort4*)(Xh + ob) = hh;
  *(ushort4*)(Xl + ob) = ll;
}

// ---------- pregate GEMM (split-bf16 MFMA, 128x128 tile, 4 waves, 4x4 frags) ----------
__global__ void __launch_bounds__(256) k_gemm(const ushort* __restrict__ Xh,
    const ushort* __restrict__ Xl,
    const ushort* __restrict__ Whf, const ushort* __restrict__ Wlf,
    const ushort* __restrict__ Whb, const ushort* __restrict__ Wlb,
    const float* __restrict__ bPf,  const float* __restrict__ bPb,
    float* __restrict__ preg, int D, int t0, int TCc) {
  int dir = blockIdx.z;
  const ushort* WhD = dir ? Whb : Whf;
  const ushort* WlD = dir ? Wlb : Wlf;
  const float*  bPD = dir ? bPb  : bPf;
  int mt = blockIdx.x, nt = blockIdx.y;
  __shared__ __align__(16) ushort Ah[128*LDA], Al[128*LDA], Bh[128*LDA], Bl[128*LDA];
  int tid = threadIdx.x;
  int lane = tid & 63, wid = tid >> 6;
  int wm = wid >> 1, wn = wid & 1;
  int l15 = lane & 15, l4 = lane >> 4;

  // staging slots (fixed per thread): idx = c*256+tid -> row=idx>>3, ch=idx&7
  size_t abase[4], wbase[4];
  int soff[4];
  #pragma unroll
  for (int c = 0; c < 4; ++c) {
    int idx = c * 256 + tid;
    int row = idx >> 3, ch = idx & 7;
    int r = mt * 128 + row;
    int s = r >> 6, n = r & 63;
    int ttt = dir ? (T_ - 1 - (t0 + s)) : (t0 + s);
    abase[c] = ((size_t)n * T_ + ttt) * D + ch * 8;
    wbase[c] = (size_t)(nt * 128 + row) * D + ch * 8;
    soff[c]  = row * LDA + ch * 8;
  }
  int arow[4], brow[4];
  #pragma unroll
  for (int f = 0; f < 4; ++f) {
    arow[f] = (wm * 64 + f * 16 + l15) * LDA + (l4 << 3);
    brow[f] = (wn * 64 + f * 16 + l15) * LDA + (l4 << 3);
  }

  f32x4v acc[4][4];
  #pragma unroll
  for (int a = 0; a < 4; ++a)
    #pragma unroll
    for (int b = 0; b < 4; ++b) acc[a][b] = (f32x4v){0.f,0.f,0.f,0.f};

  for (int k0 = 0; k0 < D; k0 += 64) {
    __syncthreads();
    #pragma unroll
    for (int c = 0; c < 4; ++c) {
      *(short8*)(Ah + soff[c]) = *(const short8*)(Xh  + abase[c] + k0);
      *(short8*)(Al + soff[c]) = *(const short8*)(Xl  + abase[c] + k0);
      *(short8*)(Bh + soff[c]) = *(const short8*)(WhD + wbase[c] + k0);
      *(short8*)(Bl + soff[c]) = *(const short8*)(WlD + wbase[c] + k0);
    }
    __syncthreads();
    #pragma unroll
    for (int ks = 0; ks < 2; ++ks) {
      bf16x8 ah[4], al[4], bh[4], bl[4];
      #pragma unroll
      for (int mf = 0; mf < 4; ++mf) {
        ah[mf] = __builtin_bit_cast(bf16x8, *(const short8*)(Ah + arow[mf] + ks*32));
        al[mf] = __builtin_bit_cast(bf16x8, *(const short8*)(Al + arow[mf] + ks*32));
      }
      #pragma unroll
      for (int nf = 0; nf < 4; ++nf) {
        bh[nf] = __builtin_bit_cast(bf16x8, *(const short8*)(Bh + brow[nf] + ks*32));
        bl[nf] = __builtin_bit_cast(bf16x8, *(const short8*)(Bl + brow[nf] + ks*32));
      }
      #pragma unroll
      for (int mf = 0; mf < 4; ++mf)
        #pragma unroll
        for (int nf = 0; nf < 4; ++nf) {
          acc[mf][nf] = __builtin_amdgcn_mfma_f32_16x16x32_bf16(ah[mf], bh[nf], acc[mf][nf], 0,0,0);
          acc[mf][nf] = __builtin_amdgcn_mfma_f32_16x16x32_bf16(ah[mf], bl[nf], acc[mf][nf], 0,0,0);
          acc[mf][nf] = __builtin_amdgcn_mfma_f32_16x16x32_bf16(al[mf], bh[nf], acc[mf][nf], 0,0,0);
        }
    }
  }
  // epilogue: bias + store (D row = 4*l4+reg, col = l15)
  float bias[4];
  #pragma unroll
  for (int nf = 0; nf < 4; ++nf) bias[nf] = bPD[nt*128 + wn*64 + nf*16 + l15];
  #pragma unroll
  for (int mf = 0; mf < 4; ++mf)
    #pragma unroll
    for (int nf = 0; nf < 4; ++nf) {
      int col = nt*128 + wn*64 + nf*16 + l15;
      #pragma unroll
      for (int rr = 0; rr < 4; ++rr) {
        int r = mt*128 + wm*64 + mf*16 + (l4 << 2) + rr;
        int s = r >> 6, n = r & 63;
        preg[(((size_t)dir * TCc + s) * 64 + n) * 2048 + col] = acc[mf][nf][rr] + bias[nf];
      }
    }
}

// ---------- main recurrence: 256 blocks x 1 wave, weights in registers (split-bf16 MFMA) ----------
__global__ void __launch_bounds__(64) k_rec(const float* __restrict__ preg,
    const float* __restrict__ whhf, const float* __restrict__ whhb,
    float* __restrict__ h_out,
    ushort* __restrict__ hH, ushort* __restrict__ hL,
    float* __restrict__ cst, int* __restrict__ counter, int t0, int TCc) {
  int dir = blockIdx.x >> 7, ublk = blockIdx.x & 127;
  const float* whh = dir ? whhb : whhf;
  int l = threadIdx.x;
  int l15 = l & 15, l4 = l >> 4;
  // A-fragment identity: row g = l15 (g = ul*4+q), k-chunk = l4
  int q = l15 & 3, ul = l15 >> 2;
  int u_gA = (ublk << 2) + ul;
  // output identity: unit = l4, q = reg, n = nf*16 + l15
  int ugo = (ublk << 2) + l4;

  bf16x8 ah[16], al[16];
  const float* wrow = whh + ((size_t)(q * 512 + u_gA)) * 512 + (l4 << 3);
  #pragma unroll
  for (int ks = 0; ks < 16; ++ks) {
    float4 w0 = *(const float4*)(wrow + ks * 32);
    float4 w1 = *(const float4*)(wrow + ks * 32 + 4);
    float wf[8] = {w0.x,w0.y,w0.z,w0.w, w1.x,w1.y,w1.z,w1.w};
    short8 h8, l8;
    #pragma unroll
    for (int j = 0; j < 8; ++j) {
      ushort hh_, ll_; bsplit(wf[j], hh_, ll_);
      h8[j] = (short)hh_; l8[j] = (short)ll_;
    }
    ah[ks] = __builtin_bit_cast(bf16x8, h8);
    al[ks] = __builtin_bit_cast(bf16x8, l8);
  }

  float cv[4] = {0.f, 0.f, 0.f, 0.f};
  if (t0 != 0) {
    #pragma unroll
    for (int nf = 0; nf < 4; ++nf)
      cv[nf] = cst[(dir << 15) + (ugo << 6) + (nf << 4) + l15];
  }

  #pragma unroll 1
  for (int s = 0; s < TCc; ++s) {
    int t = t0 + s;
    int tt = dir ? (T_ - 1 - t) : t;
    f32x4v acc[4];
    #pragma unroll
    for (int nf = 0; nf < 4; ++nf)
      acc[nf] = *(const f32x4v*)(preg + (((size_t)dir * TCc + s) * 64 + ((nf << 4) + l15)) * 2048 + (ugo << 2));
    if (t > 0) {
      int ph = (t - 1) & 1;
      const ushort* bhb = hH + (size_t)((dir << 1) | ph) * 32768;
      const ushort* blb = hL + (size_t)((dir << 1) | ph) * 32768;
      #pragma unroll
      for (int ks = 0; ks < 16; ++ks) {
        #pragma unroll
        for (int nf = 0; nf < 4; ++nf) {
          int off = (((nf << 4) + l15) << 9) + (ks << 5) + (l4 << 3);
          bf16x8 bh = __builtin_bit_cast(bf16x8, *(const short8*)(bhb + off));
          bf16x8 bl = __builtin_bit_cast(bf16x8, *(const short8*)(blb + off));
          acc[nf] = __builtin_amdgcn_mfma_f32_16x16x32_bf16(ah[ks], bh, acc[nf], 0,0,0);
          acc[nf] = __builtin_amdgcn_mfma_f32_16x16x32_bf16(al[ks], bh, acc[nf], 0,0,0);
          acc[nf] = __builtin_amdgcn_mfma_f32_16x16x32_bf16(ah[ks], bl, acc[nf], 0,0,0);
        }
      }
    }
    #pragma unroll
    for (int nf = 0; nf < 4; ++nf) {
      float ig = sigf(acc[nf][0]), fg = sigf(acc[nf][1]);
      float gg = tanhf_(acc[nf][2]), og = sigf(acc[nf][3]);
      cv[nf] = (t == 0) ? (ig * gg) : (fg * cv[nf] + ig * gg);
      float h = og * tanhf_(cv[nf]);
      int n = (nf << 4) + l15;
      h_out[((size_t)tt * 64 + n) * 1024 + (dir << 9) + ugo] = h;
      ushort hh_, hl_; bsplit(h, hh_, hl_);
      size_t hoff = (size_t)((dir << 1) | (t & 1)) * 32768 + ((size_t)n << 9) + ugo;
      hH[hoff] = hh_; hL[hoff] = hl_;
    }
    // grid barrier (256 one-wave blocks, all co-resident)
    __threadfence();
    if (l == 0) {
      atomicAdd(counter, 1);
      int target = (s + 1) << 8;
      while (__hip_atomic_load(counter, __ATOMIC_RELAXED, __HIP_MEMORY_SCOPE_AGENT) < target)
        __builtin_amdgcn_s_sleep(2);
    }
    __threadfence();
  }
  #pragma unroll
  for (int nf = 0; nf < 4; ++nf)
    cst[(dir << 15) + (ugo << 6) + (nf << 4) + l15] = cv[nf];
}

// ---------- classifier (h layout [t][n][1024]) ----------
__global__ void __launch_bounds__(256) k_cls(const float* __restrict__ h,
                                             const float* __restrict__ Wc,
                                             const float* __restrict__ bc,
                                             float* __restrict__ out) {
  int n = blockIdx.x, tid = threadIdx.x;
  float p0 = 0.f, p1 = 0.f, p2 = 0.f;
  for (int j = tid; j < 1024; j += 256) {
    int t = (j < 512) ? (T_ - 1) : 0;
    float f = h[((size_t)t * 64 + n) * 1024 + j];
    p0 += f * Wc[j]; p1 += f * Wc[1024 + j]; p2 += f * Wc[2048 + j];
  }
  #pragma unroll
  for (int o = 32; o; o >>= 1) {
    p0 += __shfl_xor(p0, o, 64);
    p1 += __shfl_xor(p1, o, 64);
    p2 += __shfl_xor(p2, o, 64);
  }
  __shared__ float red[4][3];
  int lane = tid & 63, wv = tid >> 6;
  if (lane == 0) { red[wv][0] = p0; red[wv][1] = p1; red[wv][2] = p2; }
  __syncthreads();
  if (tid < 3)
    out[n * 3 + tid] = red[0][tid] + red[1][tid] + red[2][tid] + red[3][tid] + bc[tid];
}

extern "C" void kernel_launch(void* const* d_in, const int* in_sizes, int n_in,
                              void* d_out, int out_size, void* d_ws, size_t ws_size,
                              hipStream_t stream) {
  (void)in_sizes; (void)n_in; (void)out_size;
  const int*   words  = (const int*)d_in[0];
  const int*   chars  = (const int*)d_in[1];
  const float* wl_emb = (const float*)d_in[2];
  const float* cl_emb = (const float*)d_in[3];
  const float* c_wih  = (const float*)d_in[4];
  const float* c_whh  = (const float*)d_in[5];
  const float* c_b    = (const float*)d_in[6];
  const float* WIH[3][2] = {
    { (const float*)d_in[7],  (const float*)d_in[10] },
    { (const float*)d_in[13], (const float*)d_in[16] },
    { (const float*)d_in[13] + (size_t)2048*1024, (const float*)d_in[16] + (size_t)2048*1024 } };
  const float* WHH[3][2] = {
    { (const float*)d_in[8],  (const float*)d_in[11] },
    { (const float*)d_in[14], (const float*)d_in[17] },
    { (const float*)d_in[14] + (size_t)2048*512, (const float*)d_in[17] + (size_t)2048*512 } };
  const float* BB[3][2] = {
    { (const float*)d_in[9],  (const float*)d_in[12] },
    { (const float*)d_in[15], (const float*)d_in[18] },
    { (const float*)d_in[15] + 2048, (const float*)d_in[18] + 2048 } };
  const float* Wc = (const float*)d_in[19];
  const float* bc = (const float*)d_in[20];

  // -------- workspace carve (float units, 256B aligned) --------
  float* wsp = (float*)d_ws;
  size_t off = 0;
  auto carve = [&](size_t nf) { float* p = wsp + off; off += (nf + 63) & ~(size_t)63; return p; };
  float* hA = carve((size_t)16384 * 1024);
  float* hB = carve((size_t)16384 * 1024);
  ushort* Xh = (ushort*)carve((size_t)16384 * 1024 / 2);
  ushort* Xl = (ushort*)carve((size_t)16384 * 1024 / 2);
  ushort* Whi[3][2]; ushort* Wlo[3][2]; float* bP[3][2];
  for (int ll = 0; ll < 3; ++ll)
    for (int d = 0; d < 2; ++d) {
      size_t nsh = (size_t)2048 * (ll ? 1024 : 320);
      Whi[ll][d] = (ushort*)carve(nsh / 2);
      Wlo[ll][d] = (ushort*)carve(nsh / 2);
      bP[ll][d]  = carve(2048);
    }
  float* preT = carve(100 * 256);
  float* whhc = carve(64 * 256);
  ushort* hH = (ushort*)carve((size_t)2 * 2 * 64 * 512 / 2);
  ushort* hL = (ushort*)carve((size_t)2 * 2 * 64 * 512 / 2);
  float* cst = carve((size_t)2 * 512 * 64);
  int* counter = (int*)carve(64);
  size_t wsFloats = ws_size / 4;
  int TCc = 256;
  while (TCc > 16 && off + (size_t)2 * TCc * 64 * 2048 > wsFloats) TCc >>= 1;
  float* preg = carve((size_t)2 * TCc * 64 * 2048);
  if (off > wsFloats) return;   // insufficient workspace -> loud validation failure

  // -------- weight conversion / permutes --------
  for (int ll = 0; ll < 3; ++ll)
    for (int d = 0; d < 2; ++d) {
      int D = ll ? 1024 : 320;
      int total4 = 2048 * (D >> 2);
      k_cvt_w<<<(total4 + 255)/256, 256, 0, stream>>>(WIH[ll][d], Whi[ll][d], Wlo[ll][d], D);
      k_perm_b<<<8, 256, 0, stream>>>(BB[ll][d], bP[ll][d]);
    }
  k_perm_hh_char<<<64, 256, 0, stream>>>(c_whh, whhc);

  // -------- embeddings + char LSTM (write layer-0 input bf16 hi/lo) --------
  k_pret<<<100, 256, 0, stream>>>(cl_emb, c_wih, c_b, preT);
  k_word_emb<<<16384, 256, 0, stream>>>(words, wl_emb, Xh, Xl);
  k_char<<<256, 256, 0, stream>>>(chars, preT, whhc, Xh, Xl);

  // -------- 3 stacked BiLSTM layers --------
  for (int ll = 0; ll < 3; ++ll) {
    float* ho = (ll == 1) ? hB : hA;
    int D = ll ? 1024 : 320;
    if (ll > 0) {
      const float* hin = (ll == 1) ? hA : hB;
      k_cvt_h<<<16384, 256, 0, stream>>>(hin, Xh, Xl);
    }
    for (int t0 = 0; t0 < T_; t0 += TCc) {
      dim3 g(TCc / 2, 16, 2);
      k_gemm<<<g, 256, 0, stream>>>(Xh, Xl, Whi[ll][0], Wlo[ll][0], Whi[ll][1], Wlo[ll][1],
                                    bP[ll][0], bP[ll][1], preg, D, t0, TCc);
      hipMemsetAsync(counter, 0, 4, stream);
      k_rec<<<256, 64, 0, stream>>>(preg, WHH[ll][0], WHH[ll][1], ho, hH, hL,
                                    cst, counter, t0, TCc);
    }
  }

  // -------- classifier --------
  k_cls<<<64, 256, 0, stream>>>(hA, Wc, bc, (float*)d_out);
}

// Round 3
// 17571.362 us; speedup vs baseline: 3.3995x; 1.5757x over previous
//
#include <hip/hip_runtime.h>
#include <math.h>

#define T_   256
#define C_   16
#define LDA  72   // ushort row stride in GEMM LDS tiles (144B = 9*16B: aligned, 2-way banks)

typedef float    f32x4  __attribute__((ext_vector_type(4)));
typedef _Float16 f16x8  __attribute__((ext_vector_type(8)));
typedef short    short8 __attribute__((ext_vector_type(8)));

__device__ __forceinline__ float sigf(float x)  { return 1.0f/(1.0f + __expf(-x)); }
__device__ __forceinline__ float tanhf_(float x){ return 1.0f - 2.0f/(1.0f + __expf(2.0f*x)); }

__device__ __forceinline__ void fsplit(float w, ushort& hi, ushort& lo) {
  _Float16 h = (_Float16)w;
  _Float16 l2 = (_Float16)(w - (float)h);
  hi = __builtin_bit_cast(ushort, h);
  lo = __builtin_bit_cast(ushort, l2);
}
__device__ __forceinline__ ushort f16b(float w) {
  _Float16 h = (_Float16)w; return __builtin_bit_cast(ushort, h);
}
__device__ __forceinline__ float f16f(ushort b) {
  return (float)__builtin_bit_cast(_Float16, b);
}

// ================= k_prep: ALL weight prep in one node =================
// blocks [0,100): preT; [100,164): whhc; [164,212): bP; [212,9684): Wih fp16 pairs
struct PrepArgs {
  const float *cl_emb, *c_wih, *c_b, *c_whh;
  const float *wih[6];
  const float *bb[6];
  ushort *Wh[6], *Wl[6];
  float *preT, *whhc, *bP;
};

__global__ void __launch_bounds__(256) k_prep(PrepArgs A) {
  __shared__ float e[64];
  int b = blockIdx.x, tid = threadIdx.x;
  if (b < 100) {
    // char pregate table: preT[v][u*4+q] = b[q*64+u] + renorm(cl_emb[v]).wih[q*64+u]
    if (tid < 64) e[tid] = A.cl_emb[b*64 + tid];
    __syncthreads();
    float ss = 0.f;
    #pragma unroll 8
    for (int k = 0; k < 64; ++k) ss += e[k]*e[k];
    float nn = sqrtf(ss);
    float scl = (nn > 1.0f) ? 1.0f/nn : 1.0f;
    int u = tid >> 2, q = tid & 3;
    const float* wrow = A.c_wih + (q*64 + u)*64;
    float acc = 0.f;
    #pragma unroll 8
    for (int k = 0; k < 64; ++k) acc += e[k]*wrow[k];
    A.preT[b*256 + tid] = A.c_b[q*64 + u] + scl*acc;
  } else if (b < 164) {
    int i = (b - 100)*256 + tid;     // 16384
    int k = i >> 8, rem = i & 255, u = rem >> 2, q = rem & 3;
    A.whhc[i] = A.c_whh[(q*64 + u)*64 + k];
  } else if (b < 212) {
    int i = (b - 164)*256 + tid;     // 12288
    int ld = i >> 11, j = i & 2047, u = j >> 2, q = j & 3;
    A.bP[i] = A.bb[ld][q*512 + u];
  } else {
    int idx = b - 212;
    int ld, off, D;
    if (idx < 1280) { ld = idx / 640; off = idx - ld*640; D = 320; }
    else { idx -= 1280; ld = 2 + (idx >> 11); off = idx & 2047; D = 1024; }
    int i4 = off*256 + tid;
    int D4 = D >> 2;
    int g4 = i4 / D4, k4 = i4 - g4*D4;
    int u = g4 >> 2, q = g4 & 3;
    float4 v = *(const float4*)(A.wih[ld] + (size_t)(q*512 + u)*D + (k4 << 2));
    ushort4 hh, ll;
    fsplit(v.x, hh.x, ll.x); fsplit(v.y, hh.y, ll.y);
    fsplit(v.z, hh.z, ll.z); fsplit(v.w, hh.w, ll.w);
    *(ushort4*)(A.Wh[ld] + (size_t)g4*D + (k4 << 2)) = hh;
    *(ushort4*)(A.Wl[ld] + (size_t)g4*D + (k4 << 2)) = ll;
  }
}

// ================= k_wordchar: word emb + char LSTM in one node =================
__global__ void __launch_bounds__(256) k_wordchar(const int* __restrict__ words,
    const int* __restrict__ chars, const float* __restrict__ wl_emb,
    const float* __restrict__ preT, const float* __restrict__ whhc,
    ushort* __restrict__ Xf) {
  __shared__ float sh[2*64*68];
  int b = blockIdx.x, tid = threadIdx.x;
  if (b >= 256) {
    // ---- word embedding + renorm ----
    int tok = b - 256;
    int row = words[tok];
    float e = wl_emb[(size_t)row*256 + tid];
    float ss = e*e;
    #pragma unroll
    for (int o = 32; o; o >>= 1) ss += __shfl_xor(ss, o, 64);
    int lane = tid & 63, wv = tid >> 6;
    if (lane == 0) sh[wv] = ss;
    __syncthreads();
    if (tid == 0) {
      float s2 = sh[0] + sh[1] + sh[2] + sh[3];
      float nn = sqrtf(s2);
      sh[4] = (nn > 1.0f) ? 1.0f/nn : 1.0f;
    }
    __syncthreads();
    Xf[(size_t)tok*320 + tid] = f16b(e*sh[4]);
    return;
  }
  // ---- char LSTM: 64 sequences per block, h ping-pong in LDS ----
  int u = tid & 63, sg = tid >> 6;
  int sbase = b*64 + sg*16;
  float c[16];
  float4 acc[16];
  for (int t = 0; t < C_; ++t) {
    #pragma unroll
    for (int i = 0; i < 16; ++i) {
      int ch = chars[(sbase + i)*C_ + t];
      acc[i] = *(const float4*)(preT + ch*256 + (u << 2));
    }
    if (t > 0) {
      const float* hp = sh + ((t - 1) & 1)*(64*68) + (sg << 4);
      #pragma unroll 2
      for (int k = 0; k < 64; ++k) {
        float4 w = *(const float4*)(whhc + (k << 8) + (u << 2));
        const float* hr = hp + k*68;
        float4 h0 = *(const float4*)(hr + 0);
        float4 h1 = *(const float4*)(hr + 4);
        float4 h2 = *(const float4*)(hr + 8);
        float4 h3 = *(const float4*)(hr + 12);
        float hv[16] = {h0.x,h0.y,h0.z,h0.w, h1.x,h1.y,h1.z,h1.w,
                        h2.x,h2.y,h2.z,h2.w, h3.x,h3.y,h3.z,h3.w};
        #pragma unroll
        for (int i = 0; i < 16; ++i) {
          acc[i].x += w.x*hv[i]; acc[i].y += w.y*hv[i];
          acc[i].z += w.z*hv[i]; acc[i].w += w.w*hv[i];
        }
      }
    }
    float* hw = sh + (t & 1)*(64*68);
    #pragma unroll
    for (int i = 0; i < 16; ++i) {
      float ig = sigf(acc[i].x), fg = sigf(acc[i].y);
      float gg = tanhf_(acc[i].z), og = sigf(acc[i].w);
      float cc = (t == 0) ? (ig*gg) : (fg*c[i] + ig*gg);
      c[i] = cc;
      float hh = og*tanhf_(cc);
      hw[u*68 + (sg << 4) + i] = hh;
      if (t == C_-1) Xf[(size_t)(sbase + i)*320 + 256 + u] = f16b(hh);
    }
    __syncthreads();
  }
}

// ================= pregate GEMM (fp16 A single-term, W hi/lo pair) =================
// preg layout: [dir][s][g16=0..127][n=0..63][16 floats]
__global__ void __launch_bounds__(256) k_gemm(const ushort* __restrict__ Xf,
    const ushort* __restrict__ Whf, const ushort* __restrict__ Wlf,
    const ushort* __restrict__ Whb, const ushort* __restrict__ Wlb,
    const float* __restrict__ bPf, const float* __restrict__ bPb,
    float* __restrict__ preg, int D, int t0, int TCc, int* __restrict__ counters) {
  int dir = blockIdx.z;
  const ushort* WhD = dir ? Whb : Whf;
  const ushort* WlD = dir ? Wlb : Wlf;
  const float*  bPD = dir ? bPb : bPf;
  int mt = blockIdx.x, nt = blockIdx.y;
  int tid = threadIdx.x;
  // fold the barrier-counter reset into this kernel (one block does it)
  if (tid < 2 && mt == 0 && nt == 0 && dir == 0) counters[tid << 5] = 0;

  __shared__ __align__(16) ushort As[128*LDA], Bh[128*LDA], Bl[128*LDA];
  int lane = tid & 63, wid = tid >> 6;
  int wm = wid >> 1, wn = wid & 1;
  int l15 = lane & 15, l4 = lane >> 4;

  size_t abase[4], wbase[4]; int soff[4];
  #pragma unroll
  for (int c = 0; c < 4; ++c) {
    int idx = c*256 + tid;
    int row = idx >> 3, ch = idx & 7;
    int r = mt*128 + row, s = r >> 6, n = r & 63;
    int ttt = dir ? (T_ - 1 - (t0 + s)) : (t0 + s);
    abase[c] = ((size_t)n*T_ + ttt)*D + ch*8;
    wbase[c] = (size_t)(nt*128 + row)*D + ch*8;
    soff[c]  = row*LDA + ch*8;
  }
  int arow[4], brow[4];
  #pragma unroll
  for (int f = 0; f < 4; ++f) {
    arow[f] = (wm*64 + f*16 + l15)*LDA + (l4 << 3);
    brow[f] = (wn*64 + f*16 + l15)*LDA + (l4 << 3);
  }

  f32x4 acc[4][4];
  #pragma unroll
  for (int a = 0; a < 4; ++a)
    #pragma unroll
    for (int bq = 0; bq < 4; ++bq) acc[a][bq] = (f32x4){0.f,0.f,0.f,0.f};

  for (int k0 = 0; k0 < D; k0 += 64) {
    __syncthreads();
    #pragma unroll
    for (int c = 0; c < 4; ++c) {
      *(short8*)(As + soff[c]) = *(const short8*)(Xf  + abase[c] + k0);
      *(short8*)(Bh + soff[c]) = *(const short8*)(WhD + wbase[c] + k0);
      *(short8*)(Bl + soff[c]) = *(const short8*)(WlD + wbase[c] + k0);
    }
    __syncthreads();
    #pragma unroll
    for (int ks = 0; ks < 2; ++ks) {
      f16x8 av[4], bhv[4], blv[4];
      #pragma unroll
      for (int mf = 0; mf < 4; ++mf)
        av[mf] = __builtin_bit_cast(f16x8, *(const short8*)(As + arow[mf] + ks*32));
      #pragma unroll
      for (int nf = 0; nf < 4; ++nf) {
        bhv[nf] = __builtin_bit_cast(f16x8, *(const short8*)(Bh + brow[nf] + ks*32));
        blv[nf] = __builtin_bit_cast(f16x8, *(const short8*)(Bl + brow[nf] + ks*32));
      }
      #pragma unroll
      for (int mf = 0; mf < 4; ++mf)
        #pragma unroll
        for (int nf = 0; nf < 4; ++nf) {
          acc[mf][nf] = __builtin_amdgcn_mfma_f32_16x16x32_f16(av[mf], bhv[nf], acc[mf][nf], 0,0,0);
          acc[mf][nf] = __builtin_amdgcn_mfma_f32_16x16x32_f16(av[mf], blv[nf], acc[mf][nf], 0,0,0);
        }
    }
  }
  float bias[4];
  #pragma unroll
  for (int nf = 0; nf < 4; ++nf) bias[nf] = bPD[nt*128 + wn*64 + nf*16 + l15];
  #pragma unroll
  for (int mf = 0; mf < 4; ++mf)
    #pragma unroll
    for (int nf = 0; nf < 4; ++nf) {
      int g16 = nt*8 + wn*4 + nf;
      #pragma unroll
      for (int rr = 0; rr < 4; ++rr) {
        int r = mt*128 + wm*64 + mf*16 + (l4 << 2) + rr;
        int s = r >> 6, n = r & 63;
        preg[((size_t)(dir*TCc + s)*128 + g16)*1024 + n*16 + l15] = acc[mf][nf][rr] + bias[nf];
      }
    }
}

// ================= main recurrence: 256x1-wave blocks, per-dir grid barrier =================
__global__ void __launch_bounds__(64) k_rec(const float* __restrict__ preg,
    const float* __restrict__ whhf, const float* __restrict__ whhb,
    ushort* __restrict__ XO,        // next-layer input, fp16 [n][t][1024]
    ushort* __restrict__ hF,        // [(dir<<1)|phase][n][512] fp16
    float* __restrict__ cst, int* __restrict__ counters, int t0, int TCc,
    int doCls, const float* __restrict__ Wc, const float* __restrict__ bc,
    float* __restrict__ outp) {
  int dir = blockIdx.x >> 7, ublk = blockIdx.x & 127;
  const float* whh = dir ? whhb : whhf;
  int l = threadIdx.x;
  int l15 = l & 15, l4 = l >> 4;
  int q = l15 & 3, ulq = l15 >> 2;
  int uga = (ublk << 2) + ulq;    // A-frag W row = q*512 + uga
  int ugo = (ublk << 2) + l4;     // output unit identity
  __shared__ ushort hs[256];

  // ---- load this block's Whh slice into registers as fp16 hi/lo pair ----
  f16x8 ah[16], al[16];
  {
    const float* wrow = whh + ((size_t)(q*512 + uga))*512 + (l4 << 3);
    #pragma unroll
    for (int ks = 0; ks < 16; ++ks) {
      float4 w0 = *(const float4*)(wrow + ks*32);
      float4 w1 = *(const float4*)(wrow + ks*32 + 4);
      float wf[8] = {w0.x,w0.y,w0.z,w0.w, w1.x,w1.y,w1.z,w1.w};
      short8 h8, l8;
      #pragma unroll
      for (int j = 0; j < 8; ++j) {
        ushort hb_, lb_; fsplit(wf[j], hb_, lb_);
        h8[j] = (short)hb_; l8[j] = (short)lb_;
      }
      ah[ks] = __builtin_bit_cast(f16x8, h8);
      al[ks] = __builtin_bit_cast(f16x8, l8);
    }
  }

  float cv[4] = {0.f, 0.f, 0.f, 0.f};
  if (t0 != 0) {
    #pragma unroll
    for (int nf = 0; nf < 4; ++nf)
      cv[nf] = cst[(dir << 15) + (ugo << 6) + (nf << 4) + l15];
  }

  int* ctr = counters + (dir << 5);
  #pragma unroll 1
  for (int s = 0; s < TCc; ++s) {
    int t = t0 + s;
    int tt = dir ? (T_ - 1 - t) : t;
    const float* pb = preg + ((size_t)(dir*TCc + s)*128 + ublk)*1024;
    f32x4 acc[4];
    #pragma unroll
    for (int nf = 0; nf < 4; ++nf)
      acc[nf] = *(const f32x4*)(pb + ((nf << 4) + l15)*16 + (l4 << 2));
    if (t > 0) {
      const ushort* hb = hF + (size_t)((dir << 1) | ((t - 1) & 1))*32768;
      #pragma unroll
      for (int ks = 0; ks < 16; ++ks) {
        #pragma unroll
        for (int nf = 0; nf < 4; ++nf) {
          f16x8 bv = __builtin_bit_cast(f16x8,
              *(const short8*)(hb + (((nf << 4) + l15) << 9) + (ks << 5) + (l4 << 3)));
          acc[nf] = __builtin_amdgcn_mfma_f32_16x16x32_f16(ah[ks], bv, acc[nf], 0,0,0);
          acc[nf] = __builtin_amdgcn_mfma_f32_16x16x32_f16(al[ks], bv, acc[nf], 0,0,0);
        }
      }
    }
    #pragma unroll
    for (int nf = 0; nf < 4; ++nf) {
      float ig = sigf(acc[nf][0]), fg = sigf(acc[nf][1]);
      float gg = tanhf_(acc[nf][2]), og = sigf(acc[nf][3]);
      cv[nf] = (t == 0) ? (ig*gg) : (fg*cv[nf] + ig*gg);
      float h = og*tanhf_(cv[nf]);
      hs[(((nf << 4) + l15) << 2) + l4] = f16b(h);   // LDS transpose: [n][u_local]
    }
    // lane l == batch n: gather its 4 unit-values (8B) and store coalesced-ish
    ushort4 hv = *(const ushort4*)(hs + (l << 2));
    *(ushort4*)(hF + (size_t)((dir << 1) | (t & 1))*32768 + ((size_t)l << 9) + (ublk << 2)) = hv;
    *(ushort4*)(XO + ((size_t)l*T_ + tt)*1024 + (dir << 9) + (ublk << 2)) = hv;
    // ---- per-direction grid barrier (128 one-wave blocks, co-resident) ----
    __threadfence();
    if (l == 0) {
      atomicAdd(ctr, 1);
      int target = (s + 1) << 7;
      while (__hip_atomic_load(ctr, __ATOMIC_RELAXED, __HIP_MEMORY_SCOPE_AGENT) < target)
        __builtin_amdgcn_s_sleep(1);
    }
    __threadfence();
  }
  #pragma unroll
  for (int nf = 0; nf < 4; ++nf)
    cst[(dir << 15) + (ugo << 6) + (nf << 4) + l15] = cv[nf];

  // ---- fused classifier (final layer, final chunk): block 0, lane = n ----
  if (doCls && blockIdx.x == 0) {
    if (l == 0) {
      while (__hip_atomic_load(counters + 32, __ATOMIC_RELAXED, __HIP_MEMORY_SCOPE_AGENT) < (TCc << 7))
        __builtin_amdgcn_s_sleep(1);
    }
    __threadfence();
    const ushort* f0 = hF + (size_t)1*32768 + ((size_t)l << 9);  // fwd h(T-1), phase (255&1)=1
    const ushort* f1 = hF + (size_t)3*32768 + ((size_t)l << 9);  // bwd h(t=0), stored at s=255
    float p0 = bc[0], p1 = bc[1], p2 = bc[2];
    for (int j = 0; j < 512; ++j) {
      float v = f16f(f0[j]);
      p0 += v*Wc[j]; p1 += v*Wc[1024 + j]; p2 += v*Wc[2048 + j];
    }
    for (int j = 0; j < 512; ++j) {
      float v = f16f(f1[j]);
      p0 += v*Wc[512 + j]; p1 += v*Wc[1536 + j]; p2 += v*Wc[2560 + j];
    }
    outp[l*3 + 0] = p0; outp[l*3 + 1] = p1; outp[l*3 + 2] = p2;
  }
}

extern "C" void kernel_launch(void* const* d_in, const int* in_sizes, int n_in,
                              void* d_out, int out_size, void* d_ws, size_t ws_size,
                              hipStream_t stream) {
  (void)in_sizes; (void)n_in; (void)out_size;
  const int*   words  = (const int*)d_in[0];
  const int*   chars  = (const int*)d_in[1];
  const float* wl_emb = (const float*)d_in[2];
  const float* cl_emb = (const float*)d_in[3];
  const float* c_wih  = (const float*)d_in[4];
  const float* c_whh  = (const float*)d_in[5];
  const float* c_b    = (const float*)d_in[6];
  const float* WIH[6] = {
    (const float*)d_in[7],  (const float*)d_in[10],
    (const float*)d_in[13], (const float*)d_in[16],
    (const float*)d_in[13] + (size_t)2048*1024, (const float*)d_in[16] + (size_t)2048*1024 };
  const float* WHH[3][2] = {
    { (const float*)d_in[8],  (const float*)d_in[11] },
    { (const float*)d_in[14], (const float*)d_in[17] },
    { (const float*)d_in[14] + (size_t)2048*512, (const float*)d_in[17] + (size_t)2048*512 } };
  const float* BB[6] = {
    (const float*)d_in[9],  (const float*)d_in[12],
    (const float*)d_in[15], (const float*)d_in[18],
    (const float*)d_in[15] + 2048, (const float*)d_in[18] + 2048 };
  const float* Wc = (const float*)d_in[19];
  const float* bc = (const float*)d_in[20];

  // -------- workspace carve --------
  float* wsp = (float*)d_ws;
  size_t off = 0;
  auto carve = [&](size_t nf) { float* p = wsp + off; off += (nf + 63) & ~(size_t)63; return p; };
  ushort* XA = (ushort*)carve((size_t)16384*1024/2);
  ushort* XB = (ushort*)carve((size_t)16384*1024/2);
  ushort* Wh6[6]; ushort* Wl6[6];
  for (int ld = 0; ld < 6; ++ld) {
    size_t D = (ld < 2) ? 320 : 1024;
    Wh6[ld] = (ushort*)carve((size_t)2048*D/2);
    Wl6[ld] = (ushort*)carve((size_t)2048*D/2);
  }
  float* bP   = carve(6*2048);
  float* preT = carve(100*256);
  float* whhc = carve(64*256);
  ushort* hF  = (ushort*)carve((size_t)4*32768/2);
  float* cst  = carve((size_t)2*512*64);
  int* counters = (int*)carve(64);
  size_t wsFloats = ws_size / 4;
  int TCc = 256;
  while (TCc > 16 && off + (size_t)2*TCc*64*2048 > wsFloats) TCc >>= 1;
  float* preg = carve((size_t)2*TCc*64*2048);
  if (off > wsFloats) return;   // insufficient workspace -> loud validation failure

  // -------- node 1: all weight prep --------
  PrepArgs pa;
  pa.cl_emb = cl_emb; pa.c_wih = c_wih; pa.c_b = c_b; pa.c_whh = c_whh;
  for (int ld = 0; ld < 6; ++ld) { pa.wih[ld] = WIH[ld]; pa.bb[ld] = BB[ld];
                                   pa.Wh[ld] = Wh6[ld]; pa.Wl[ld] = Wl6[ld]; }
  pa.preT = preT; pa.whhc = whhc; pa.bP = bP;
  k_prep<<<9684, 256, 0, stream>>>(pa);

  // -------- node 2: word embedding + char LSTM --------
  k_wordchar<<<16640, 256, 0, stream>>>(words, chars, wl_emb, preT, whhc, XA);

  // -------- 3 stacked BiLSTM layers --------
  for (int l = 0; l < 3; ++l) {
    const ushort* Xin = (l == 1) ? XB : XA;
    ushort* Xout = (l == 1) ? XA : XB;
    int D = l ? 1024 : 320;
    for (int t0 = 0; t0 < T_; t0 += TCc) {
      k_gemm<<<dim3(TCc/2, 16, 2), 256, 0, stream>>>(Xin,
          Wh6[2*l], Wl6[2*l], Wh6[2*l+1], Wl6[2*l+1],
          bP + (2*l)*2048, bP + (2*l+1)*2048, preg, D, t0, TCc, counters);
      int doCls = (l == 2 && t0 + TCc == T_) ? 1 : 0;
      k_rec<<<256, 64, 0, stream>>>(preg, WHH[l][0], WHH[l][1], Xout, hF, cst,
                                    counters, t0, TCc, doCls, Wc, bc, (float*)d_out);
    }
  }
}

// Round 4
// 13466.246 us; speedup vs baseline: 4.4358x; 1.3048x over previous
//
#include <hip/hip_runtime.h>
#include <math.h>

#define T_   256
#define C_   16
#define LDA  64   // ushort row stride in GEMM LDS tiles (128B rows + XOR swizzle)

typedef float    f32x4  __attribute__((ext_vector_type(4)));
typedef float    f32x16 __attribute__((ext_vector_type(16)));
typedef _Float16 f16x8  __attribute__((ext_vector_type(8)));
typedef short    short8 __attribute__((ext_vector_type(8)));

__device__ __forceinline__ float sigf(float x)  { return 1.0f/(1.0f + __expf(-x)); }
__device__ __forceinline__ float tanhf_(float x){ return 1.0f - 2.0f/(1.0f + __expf(2.0f*x)); }

__device__ __forceinline__ void fsplit(float w, ushort& hi, ushort& lo) {
  _Float16 h = (_Float16)w;
  _Float16 l2 = (_Float16)(w - (float)h);
  hi = __builtin_bit_cast(ushort, h);
  lo = __builtin_bit_cast(ushort, l2);
}
__device__ __forceinline__ ushort f16b(float w) {
  _Float16 h = (_Float16)w; return __builtin_bit_cast(ushort, h);
}
__device__ __forceinline__ float f16f(ushort b) {
  return (float)__builtin_bit_cast(_Float16, b);
}

// ================= k_prep: ALL weight prep in one node =================
struct PrepArgs {
  const float *cl_emb, *c_wih, *c_b, *c_whh;
  const float *wih[6];
  const float *bb[6];
  ushort *Wh[6], *Wl[6];
  float *preT, *whhc, *bP;
  int *barr;
};

__global__ void __launch_bounds__(256) k_prep(PrepArgs A) {
  __shared__ float e[64];
  int b = blockIdx.x, tid = threadIdx.x;
  if (b == 0 && tid < 64) A.barr[tid] = 0;   // zero barrier slots every launch
  if (b < 100) {
    if (tid < 64) e[tid] = A.cl_emb[b*64 + tid];
    __syncthreads();
    float ss = 0.f;
    #pragma unroll 8
    for (int k = 0; k < 64; ++k) ss += e[k]*e[k];
    float nn = sqrtf(ss);
    float scl = (nn > 1.0f) ? 1.0f/nn : 1.0f;
    int u = tid >> 2, q = tid & 3;
    const float* wrow = A.c_wih + (q*64 + u)*64;
    float acc = 0.f;
    #pragma unroll 8
    for (int k = 0; k < 64; ++k) acc += e[k]*wrow[k];
    A.preT[b*256 + tid] = A.c_b[q*64 + u] + scl*acc;
  } else if (b < 164) {
    int i = (b - 100)*256 + tid;
    int k = i >> 8, rem = i & 255, u = rem >> 2, q = rem & 3;
    A.whhc[i] = A.c_whh[(q*64 + u)*64 + k];
  } else if (b < 212) {
    int i = (b - 164)*256 + tid;
    int ld = i >> 11, j = i & 2047, u = j >> 2, q = j & 3;
    A.bP[i] = A.bb[ld][q*512 + u];
  } else {
    int idx = b - 212;
    int ld, off, D;
    if (idx < 1280) { ld = idx / 640; off = idx - ld*640; D = 320; }
    else { idx -= 1280; ld = 2 + (idx >> 11); off = idx & 2047; D = 1024; }
    int i4 = off*256 + tid;
    int D4 = D >> 2;
    int g4 = i4 / D4, k4 = i4 - g4*D4;
    int u = g4 >> 2, q = g4 & 3;
    float4 v = *(const float4*)(A.wih[ld] + (size_t)(q*512 + u)*D + (k4 << 2));
    ushort4 hh, ll;
    fsplit(v.x, hh.x, ll.x); fsplit(v.y, hh.y, ll.y);
    fsplit(v.z, hh.z, ll.z); fsplit(v.w, hh.w, ll.w);
    *(ushort4*)(A.Wh[ld] + (size_t)g4*D + (k4 << 2)) = hh;
    *(ushort4*)(A.Wl[ld] + (size_t)g4*D + (k4 << 2)) = ll;
  }
}

// ================= k_wordchar: word emb + char LSTM =================
__global__ void __launch_bounds__(256) k_wordchar(const int* __restrict__ words,
    const int* __restrict__ chars, const float* __restrict__ wl_emb,
    const float* __restrict__ preT, const float* __restrict__ whhc,
    ushort* __restrict__ Xf) {
  __shared__ float sh[2*64*68];
  int b = blockIdx.x, tid = threadIdx.x;
  if (b >= 256) {
    int tok = b - 256;
    int row = words[tok];
    float e = wl_emb[(size_t)row*256 + tid];
    float ss = e*e;
    #pragma unroll
    for (int o = 32; o; o >>= 1) ss += __shfl_xor(ss, o, 64);
    int lane = tid & 63, wv = tid >> 6;
    if (lane == 0) sh[wv] = ss;
    __syncthreads();
    if (tid == 0) {
      float s2 = sh[0] + sh[1] + sh[2] + sh[3];
      float nn = sqrtf(s2);
      sh[4] = (nn > 1.0f) ? 1.0f/nn : 1.0f;
    }
    __syncthreads();
    Xf[(size_t)tok*320 + tid] = f16b(e*sh[4]);
    return;
  }
  int u = tid & 63, sg = tid >> 6;
  int sbase = b*64 + sg*16;
  float c[16];
  float4 acc[16];
  for (int t = 0; t < C_; ++t) {
    #pragma unroll
    for (int i = 0; i < 16; ++i) {
      int ch = chars[(sbase + i)*C_ + t];
      acc[i] = *(const float4*)(preT + ch*256 + (u << 2));
    }
    if (t > 0) {
      const float* hp = sh + ((t - 1) & 1)*(64*68) + (sg << 4);
      #pragma unroll 2
      for (int k = 0; k < 64; ++k) {
        float4 w = *(const float4*)(whhc + (k << 8) + (u << 2));
        const float* hr = hp + k*68;
        float4 h0 = *(const float4*)(hr + 0);
        float4 h1 = *(const float4*)(hr + 4);
        float4 h2 = *(const float4*)(hr + 8);
        float4 h3 = *(const float4*)(hr + 12);
        float hv[16] = {h0.x,h0.y,h0.z,h0.w, h1.x,h1.y,h1.z,h1.w,
                        h2.x,h2.y,h2.z,h2.w, h3.x,h3.y,h3.z,h3.w};
        #pragma unroll
        for (int i = 0; i < 16; ++i) {
          acc[i].x += w.x*hv[i]; acc[i].y += w.y*hv[i];
          acc[i].z += w.z*hv[i]; acc[i].w += w.w*hv[i];
        }
      }
    }
    float* hw = sh + (t & 1)*(64*68);
    #pragma unroll
    for (int i = 0; i < 16; ++i) {
      float ig = sigf(acc[i].x), fg = sigf(acc[i].y);
      float gg = tanhf_(acc[i].z), og = sigf(acc[i].w);
      float cc = (t == 0) ? (ig*gg) : (fg*c[i] + ig*gg);
      c[i] = cc;
      float hh = og*tanhf_(cc);
      hw[u*68 + (sg << 4) + i] = hh;
      if (t == C_-1) Xf[(size_t)(sbase + i)*320 + 256 + u] = f16b(hh);
    }
    __syncthreads();
  }
}

// ================= pregate GEMM (fp16 A, W hi/lo pair, XOR-swizzled LDS) =================
// preg layout: [dir][s][g16=0..127][n=0..63][16 floats]
__global__ void __launch_bounds__(256) k_gemm(const ushort* __restrict__ Xf,
    const ushort* __restrict__ Whf, const ushort* __restrict__ Wlf,
    const ushort* __restrict__ Whb, const ushort* __restrict__ Wlb,
    const float* __restrict__ bPf, const float* __restrict__ bPb,
    float* __restrict__ preg, int D, int t0, int TCc) {
  int dir = blockIdx.z;
  const ushort* WhD = dir ? Whb : Whf;
  const ushort* WlD = dir ? Wlb : Wlf;
  const float*  bPD = dir ? bPb : bPf;
  int mt = blockIdx.x, nt = blockIdx.y;
  int tid = threadIdx.x;

  __shared__ __align__(16) ushort As[128*LDA], Bh[128*LDA], Bl[128*LDA];
  int lane = tid & 63, wid = tid >> 6;
  int wm = wid >> 1, wn = wid & 1;
  int l15 = lane & 15, l4 = lane >> 4;

  size_t abase[4], wbase[4]; int soff[4];
  #pragma unroll
  for (int c = 0; c < 4; ++c) {
    int idx = c*256 + tid;
    int row = idx >> 3, ch = idx & 7;
    int r = mt*128 + row, s = r >> 6, n = r & 63;
    int ttt = dir ? (T_ - 1 - (t0 + s)) : (t0 + s);
    abase[c] = ((size_t)n*T_ + ttt)*D + ch*8;
    wbase[c] = (size_t)(nt*128 + row)*D + ch*8;
    soff[c]  = row*LDA + ((ch ^ (row & 7)) << 3);   // XOR-swizzled 16B slot
  }
  int x7 = l15 & 7;
  int rA[4], rB[4];
  #pragma unroll
  for (int f = 0; f < 4; ++f) {
    rA[f] = (wm*64 + f*16 + l15)*LDA;
    rB[f] = (wn*64 + f*16 + l15)*LDA;
  }
  int o0 = (l4 ^ x7) << 3;   // ks=0 frag offset (ushorts); ks=1 -> o0^32

  f32x4 acc[4][4];
  #pragma unroll
  for (int a = 0; a < 4; ++a)
    #pragma unroll
    for (int bq = 0; bq < 4; ++bq) acc[a][bq] = (f32x4){0.f,0.f,0.f,0.f};

  for (int k0 = 0; k0 < D; k0 += 64) {
    __syncthreads();
    #pragma unroll
    for (int c = 0; c < 4; ++c) {
      *(short8*)(As + soff[c]) = *(const short8*)(Xf  + abase[c] + k0);
      *(short8*)(Bh + soff[c]) = *(const short8*)(WhD + wbase[c] + k0);
      *(short8*)(Bl + soff[c]) = *(const short8*)(WlD + wbase[c] + k0);
    }
    __syncthreads();
    #pragma unroll
    for (int ks = 0; ks < 2; ++ks) {
      int fo = ks ? (o0 ^ 32) : o0;
      f16x8 av[4], bhv[4], blv[4];
      #pragma unroll
      for (int mf = 0; mf < 4; ++mf)
        av[mf] = __builtin_bit_cast(f16x8, *(const short8*)(As + rA[mf] + fo));
      #pragma unroll
      for (int nf = 0; nf < 4; ++nf) {
        bhv[nf] = __builtin_bit_cast(f16x8, *(const short8*)(Bh + rB[nf] + fo));
        blv[nf] = __builtin_bit_cast(f16x8, *(const short8*)(Bl + rB[nf] + fo));
      }
      #pragma unroll
      for (int mf = 0; mf < 4; ++mf)
        #pragma unroll
        for (int nf = 0; nf < 4; ++nf) {
          acc[mf][nf] = __builtin_amdgcn_mfma_f32_16x16x32_f16(av[mf], bhv[nf], acc[mf][nf], 0,0,0);
          acc[mf][nf] = __builtin_amdgcn_mfma_f32_16x16x32_f16(av[mf], blv[nf], acc[mf][nf], 0,0,0);
        }
    }
  }
  float bias[4];
  #pragma unroll
  for (int nf = 0; nf < 4; ++nf) bias[nf] = bPD[nt*128 + wn*64 + nf*16 + l15];
  #pragma unroll
  for (int mf = 0; mf < 4; ++mf)
    #pragma unroll
    for (int nf = 0; nf < 4; ++nf) {
      int g16 = nt*8 + wn*4 + nf;
      #pragma unroll
      for (int rr = 0; rr < 4; ++rr) {
        int r = mt*128 + wm*64 + mf*16 + (l4 << 2) + rr;
        int s = r >> 6, n = r & 63;
        preg[((size_t)(dir*TCc + s)*128 + g16)*1024 + n*16 + l15] = acc[mf][nf][rr] + bias[nf];
      }
    }
}

// ================= main recurrence: 64 blocks x 4 waves, 32x32x16 MFMA =================
// block bi: dir = bi>>5, ublk = bi&31 owns units [ublk*16, ublk*16+16)
// wave w: gate-half gh=w&1 (32 gate rows), n-half nh=w>>1 (32 cols)
__global__ void __launch_bounds__(256, 1) k_rec(const float* __restrict__ preg,
    const float* __restrict__ whhf, const float* __restrict__ whhb,
    ushort* __restrict__ XO, ushort* __restrict__ hF, float* __restrict__ cst,
    int* __restrict__ barr, int t0, int TCc, int ebase,
    int doCls, const float* __restrict__ Wc, const float* __restrict__ bc,
    float* __restrict__ outp) {
  __shared__ ushort hs[64*16];
  __shared__ float red[64][4][3];
  int bi = blockIdx.x;
  int dir = bi >> 5, ublk = bi & 31;
  const float* whh = dir ? whhb : whhf;
  int tid = threadIdx.x, w = tid >> 6, l = tid & 63;
  int l31 = l & 31, l5 = l >> 5;
  int gh = w & 1, nh = w >> 1;
  int n_ = nh*32 + l31;
  int q = l31 & 3;
  int urow = ublk*16 + gh*8 + (l31 >> 2);
  int g16b = ublk*4 + gh*2;

  // ---- Whh slice -> registers (fp16 hi/lo), A layout: row=lane&31, k=(lane>>5)*8+j ----
  f16x8 ah[32], al[32];
  {
    const float* wr = whh + ((size_t)(q*512 + urow))*512 + l5*8;
    #pragma unroll
    for (int ks = 0; ks < 32; ++ks) {
      float4 w0 = *(const float4*)(wr + ks*16);
      float4 w1 = *(const float4*)(wr + ks*16 + 4);
      float wf[8] = {w0.x,w0.y,w0.z,w0.w, w1.x,w1.y,w1.z,w1.w};
      short8 h8, l8;
      #pragma unroll
      for (int j = 0; j < 8; ++j) {
        ushort hb_, lb_; fsplit(wf[j], hb_, lb_);
        h8[j] = (short)hb_; l8[j] = (short)lb_;
      }
      ah[ks] = __builtin_bit_cast(f16x8, h8);
      al[ks] = __builtin_bit_cast(f16x8, l8);
    }
  }
  float cv[4];
  #pragma unroll
  for (int e = 0; e < 4; ++e) {
    int u = ublk*16 + gh*8 + 2*e + l5;
    cv[e] = (t0 == 0) ? 0.f : cst[(size_t)(dir*64 + n_)*512 + u];
  }
  // prologue: preg for s=0 into acc
  f32x16 acc;
  {
    const float* pb = preg + (size_t)(dir*TCc)*131072;
    #pragma unroll
    for (int e = 0; e < 4; ++e) {
      f32x4 v = *(const f32x4*)(pb + (g16b + (e>>1))*1024 + n_*16 + 8*(e&1) + 4*l5);
      acc[4*e+0]=v[0]; acc[4*e+1]=v[1]; acc[4*e+2]=v[2]; acc[4*e+3]=v[3];
    }
  }
  int* arrd = barr + dir*32;

  #pragma unroll 1
  for (int s = 0; s < TCc; ++s) {
    int t = t0 + s;
    int tt = dir ? (T_ - 1 - t) : t;
    if (t > 0) {
      const ushort* hb = hF + (size_t)((dir<<1) | ((t-1)&1))*32768 + n_*512 + l5*8;
      #pragma unroll
      for (int ks = 0; ks < 32; ++ks) {
        f16x8 bv = __builtin_bit_cast(f16x8, *(const short8*)(hb + ks*16));
        acc = __builtin_amdgcn_mfma_f32_32x32x16_f16(ah[ks], bv, acc, 0,0,0);
        acc = __builtin_amdgcn_mfma_f32_32x32x16_f16(al[ks], bv, acc, 0,0,0);
      }
    }
    // gates: acc reg r: row m=(r&3)+8*(r>>2)+4*l5 -> unit u_loc=gh*8+2e+l5, q=r&3
    #pragma unroll
    for (int e = 0; e < 4; ++e) {
      float ig = sigf(acc[4*e+0]), fg = sigf(acc[4*e+1]);
      float gg = tanhf_(acc[4*e+2]), og = sigf(acc[4*e+3]);
      float c = (t == 0) ? (ig*gg) : (fg*cv[e] + ig*gg);
      cv[e] = c;
      float h = og*tanhf_(c);
      int ul = gh*8 + 2*e + l5;
      hs[n_*16 + (ul ^ ((n_&1)<<3))] = f16b(h);
    }
    __syncthreads();
    // cooperative coalesced store of the block's 16-unit slice
    {
      int n2 = tid >> 2, c2 = tid & 3;
      short4 hv = *(const short4*)&hs[n2*16 + ((c2 ^ ((n2&1)<<1)) << 2)];
      *(short4*)(hF + (size_t)((dir<<1)|(t&1))*32768 + n2*512 + ublk*16 + c2*4) = hv;
      if (XO) *(short4*)(XO + (size_t)n2*262144 + (size_t)tt*1024 + dir*512 + ublk*16 + c2*4) = hv;
    }
    __threadfence();            // release: h visible device-wide
    __syncthreads();
    int epoch = ebase + s + 1;
    if (tid == 0)
      __hip_atomic_store(&arrd[ublk], epoch, __ATOMIC_RELAXED, __HIP_MEMORY_SCOPE_AGENT);
    // prefetch next step's preg into acc (in flight across the spin)
    if (s + 1 < TCc) {
      const float* pb = preg + (size_t)(dir*TCc + s + 1)*131072;
      #pragma unroll
      for (int e = 0; e < 4; ++e) {
        f32x4 v = *(const f32x4*)(pb + (g16b + (e>>1))*1024 + n_*16 + 8*(e&1) + 4*l5);
        acc[4*e+0]=v[0]; acc[4*e+1]=v[1]; acc[4*e+2]=v[2]; acc[4*e+3]=v[3];
      }
    }
    if (w == 0) {               // flagless direct poll: all 32 blocks of this dir
      bool done = false;
      while (!done) {
        int v = (l < 32) ? __hip_atomic_load(&arrd[l], __ATOMIC_RELAXED, __HIP_MEMORY_SCOPE_AGENT)
                         : 0x7fffffff;
        done = (__ballot(v >= epoch) == ~0ull);
      }
    }
    __syncthreads();
    __threadfence();            // acquire: invalidate stale h
  }
  #pragma unroll
  for (int e = 0; e < 4; ++e)
    cst[(size_t)(dir*64 + n_)*512 + ublk*16 + gh*8 + 2*e + l5] = cv[e];

  // ---- fused classifier: block 0 waits for dir1, then 256-thread dot ----
  if (doCls && bi == 0) {
    int eEnd = ebase + TCc;
    if (w == 0) {
      bool done = false;
      while (!done) {
        int v = (l < 32) ? __hip_atomic_load(&barr[32 + l], __ATOMIC_RELAXED, __HIP_MEMORY_SCOPE_AGENT)
                         : 0x7fffffff;
        done = (__ballot(v >= eEnd) == ~0ull);
      }
    }
    __syncthreads();
    __threadfence();
    int n = tid >> 2, p = tid & 3;
    const ushort* f0 = hF + 32768 + n*512;       // fwd h(T-1): phase 1
    const ushort* f1 = hF + 3*32768 + n*512;     // bwd h(t=0): phase 1
    float p0 = 0.f, p1 = 0.f, p2 = 0.f;
    for (int j = p*128; j < p*128 + 128; ++j) {
      float v = f16f(f0[j]);
      p0 += v*Wc[j]; p1 += v*Wc[1024 + j]; p2 += v*Wc[2048 + j];
      float v2 = f16f(f1[j]);
      p0 += v2*Wc[512 + j]; p1 += v2*Wc[1536 + j]; p2 += v2*Wc[2560 + j];
    }
    red[n][p][0] = p0; red[n][p][1] = p1; red[n][p][2] = p2;
    __syncthreads();
    if (tid < 192) {
      int nn = tid / 3, o = tid - nn*3;
      outp[nn*3 + o] = red[nn][0][o] + red[nn][1][o] + red[nn][2][o] + red[nn][3][o] + bc[o];
    }
  }
}

extern "C" void kernel_launch(void* const* d_in, const int* in_sizes, int n_in,
                              void* d_out, int out_size, void* d_ws, size_t ws_size,
                              hipStream_t stream) {
  (void)in_sizes; (void)n_in; (void)out_size;
  const int*   words  = (const int*)d_in[0];
  const int*   chars  = (const int*)d_in[1];
  const float* wl_emb = (const float*)d_in[2];
  const float* cl_emb = (const float*)d_in[3];
  const float* c_wih  = (const float*)d_in[4];
  const float* c_whh  = (const float*)d_in[5];
  const float* c_b    = (const float*)d_in[6];
  const float* WIH[6] = {
    (const float*)d_in[7],  (const float*)d_in[10],
    (const float*)d_in[13], (const float*)d_in[16],
    (const float*)d_in[13] + (size_t)2048*1024, (const float*)d_in[16] + (size_t)2048*1024 };
  const float* WHH[3][2] = {
    { (const float*)d_in[8],  (const float*)d_in[11] },
    { (const float*)d_in[14], (const float*)d_in[17] },
    { (const float*)d_in[14] + (size_t)2048*512, (const float*)d_in[17] + (size_t)2048*512 } };
  const float* BB[6] = {
    (const float*)d_in[9],  (const float*)d_in[12],
    (const float*)d_in[15], (const float*)d_in[18],
    (const float*)d_in[15] + 2048, (const float*)d_in[18] + 2048 };
  const float* Wc = (const float*)d_in[19];
  const float* bc = (const float*)d_in[20];

  // -------- workspace carve --------
  float* wsp = (float*)d_ws;
  size_t off = 0;
  auto carve = [&](size_t nf) { float* p = wsp + off; off += (nf + 63) & ~(size_t)63; return p; };
  ushort* XA = (ushort*)carve((size_t)16384*1024/2);
  ushort* XB = (ushort*)carve((size_t)16384*1024/2);
  ushort* Wh6[6]; ushort* Wl6[6];
  for (int ld = 0; ld < 6; ++ld) {
    size_t D = (ld < 2) ? 320 : 1024;
    Wh6[ld] = (ushort*)carve((size_t)2048*D/2);
    Wl6[ld] = (ushort*)carve((size_t)2048*D/2);
  }
  float* bP   = carve(6*2048);
  float* preT = carve(100*256);
  float* whhc = carve(64*256);
  ushort* hF  = (ushort*)carve((size_t)4*32768/2);
  float* cst  = carve((size_t)2*64*512);
  int* barr   = (int*)carve(64);
  size_t wsFloats = ws_size / 4;
  int TCc = 256;
  while (TCc > 16 && off + (size_t)2*TCc*64*2048 > wsFloats) TCc >>= 1;
  float* preg = carve((size_t)2*TCc*64*2048);
  if (off > wsFloats) return;   // insufficient workspace -> loud validation failure

  // -------- node 1: all weight prep (+ barrier-slot zeroing) --------
  PrepArgs pa;
  pa.cl_emb = cl_emb; pa.c_wih = c_wih; pa.c_b = c_b; pa.c_whh = c_whh;
  for (int ld = 0; ld < 6; ++ld) { pa.wih[ld] = WIH[ld]; pa.bb[ld] = BB[ld];
                                   pa.Wh[ld] = Wh6[ld]; pa.Wl[ld] = Wl6[ld]; }
  pa.preT = preT; pa.whhc = whhc; pa.bP = bP; pa.barr = barr;
  k_prep<<<9684, 256, 0, stream>>>(pa);

  // -------- node 2: word embedding + char LSTM --------
  k_wordchar<<<16640, 256, 0, stream>>>(words, chars, wl_emb, preT, whhc, XA);

  // -------- 3 stacked BiLSTM layers --------
  for (int l = 0; l < 3; ++l) {
    const ushort* Xin = (l == 1) ? XB : XA;
    ushort* Xout = (l == 0) ? XB : ((l == 1) ? XA : nullptr);
    int D = l ? 1024 : 320;
    for (int t0 = 0; t0 < T_; t0 += TCc) {
      k_gemm<<<dim3(TCc/2, 16, 2), 256, 0, stream>>>(Xin,
          Wh6[2*l], Wl6[2*l], Wh6[2*l+1], Wl6[2*l+1],
          bP + (2*l)*2048, bP + (2*l+1)*2048, preg, D, t0, TCc);
      int doCls = (l == 2 && t0 + TCc == T_) ? 1 : 0;
      k_rec<<<64, 256, 0, stream>>>(preg, WHH[l][0], WHH[l][1], Xout, hF, cst,
                                    barr, t0, TCc, l*T_ + t0, doCls, Wc, bc, (float*)d_out);
    }
  }
}

// Round 5
// 6320.520 us; speedup vs baseline: 9.4507x; 2.1306x over previous
//
#include <hip/hip_runtime.h>
#include <math.h>

#define T_   256
#define C_   16

typedef float    f32x4  __attribute__((ext_vector_type(4)));
typedef float    f32x16 __attribute__((ext_vector_type(16)));
typedef _Float16 f16x8  __attribute__((ext_vector_type(8)));
typedef short    short8 __attribute__((ext_vector_type(8)));
typedef unsigned long long ULL;

__device__ __forceinline__ float sigf(float x)  { return 1.0f/(1.0f + __expf(-x)); }
__device__ __forceinline__ float tanhf_(float x){ return 1.0f - 2.0f/(1.0f + __expf(2.0f*x)); }

__device__ __forceinline__ void fsplit(float w, ushort& hi, ushort& lo) {
  _Float16 h = (_Float16)w;
  _Float16 l2 = (_Float16)(w - (float)h);
  hi = __builtin_bit_cast(ushort, h);
  lo = __builtin_bit_cast(ushort, l2);
}
__device__ __forceinline__ ushort f16b(float w) {
  _Float16 h = (_Float16)w; return __builtin_bit_cast(ushort, h);
}
__device__ __forceinline__ float f16f(ushort b) {
  return (float)__builtin_bit_cast(_Float16, b);
}

// LLC-coherent 16B load (bypass L1/L2 both ways; no fences needed)
#define LLCLD(dst, base, OFF) \
  asm volatile("global_load_dwordx4 %0, %1, off offset:%c2 sc0 sc1" \
               : "=v"(dst) : "v"(base), "n"(OFF) : "memory")

// ================= k_prep: ALL weight prep in one node =================
struct PrepArgs {
  const float *cl_emb, *c_wih, *c_b, *c_whh;
  const float *wih[6];
  const float *bb[6];
  ushort *Wh[6], *Wl[6];
  float *preT, *whhc, *bP;
  int *barr;
};

__global__ void __launch_bounds__(256) k_prep(PrepArgs A) {
  __shared__ float e[64];
  int b = blockIdx.x, tid = threadIdx.x;
  if (b == 0 && tid < 64) A.barr[tid] = 0;   // zero barrier slots every launch
  if (b < 100) {
    if (tid < 64) e[tid] = A.cl_emb[b*64 + tid];
    __syncthreads();
    float ss = 0.f;
    #pragma unroll 8
    for (int k = 0; k < 64; ++k) ss += e[k]*e[k];
    float nn = sqrtf(ss);
    float scl = (nn > 1.0f) ? 1.0f/nn : 1.0f;
    int u = tid >> 2, q = tid & 3;
    const float* wrow = A.c_wih + (q*64 + u)*64;
    float acc = 0.f;
    #pragma unroll 8
    for (int k = 0; k < 64; ++k) acc += e[k]*wrow[k];
    A.preT[b*256 + tid] = A.c_b[q*64 + u] + scl*acc;
  } else if (b < 164) {
    int i = (b - 100)*256 + tid;
    int k = i >> 8, rem = i & 255, u = rem >> 2, q = rem & 3;
    A.whhc[i] = A.c_whh[(q*64 + u)*64 + k];
  } else if (b < 212) {
    int i = (b - 164)*256 + tid;
    int ld = i >> 11, j = i & 2047, u = j >> 2, q = j & 3;
    A.bP[i] = A.bb[ld][q*512 + u];
  } else {
    int idx = b - 212;
    int ld, off, D;
    if (idx < 1280) { ld = idx / 640; off = idx - ld*640; D = 320; }
    else { idx -= 1280; ld = 2 + (idx >> 11); off = idx & 2047; D = 1024; }
    int i4 = off*256 + tid;
    int D4 = D >> 2;
    int g4 = i4 / D4, k4 = i4 - g4*D4;
    int u = g4 >> 2, q = g4 & 3;
    float4 v = *(const float4*)(A.wih[ld] + (size_t)(q*512 + u)*D + (k4 << 2));
    ushort4 hh, ll;
    fsplit(v.x, hh.x, ll.x); fsplit(v.y, hh.y, ll.y);
    fsplit(v.z, hh.z, ll.z); fsplit(v.w, hh.w, ll.w);
    *(ushort4*)(A.Wh[ld] + (size_t)g4*D + (k4 << 2)) = hh;
    *(ushort4*)(A.Wl[ld] + (size_t)g4*D + (k4 << 2)) = ll;
  }
}

// ================= k_wordchar: word emb + char LSTM =================
__global__ void __launch_bounds__(256) k_wordchar(const int* __restrict__ words,
    const int* __restrict__ chars, const float* __restrict__ wl_emb,
    const float* __restrict__ preT, const float* __restrict__ whhc,
    ushort* __restrict__ Xf) {
  __shared__ float sh[2*64*68];
  int b = blockIdx.x, tid = threadIdx.x;
  if (b >= 256) {
    int tok = b - 256;
    int row = words[tok];
    float e = wl_emb[(size_t)row*256 + tid];
    float ss = e*e;
    #pragma unroll
    for (int o = 32; o; o >>= 1) ss += __shfl_xor(ss, o, 64);
    int lane = tid & 63, wv = tid >> 6;
    if (lane == 0) sh[wv] = ss;
    __syncthreads();
    if (tid == 0) {
      float s2 = sh[0] + sh[1] + sh[2] + sh[3];
      float nn = sqrtf(s2);
      sh[4] = (nn > 1.0f) ? 1.0f/nn : 1.0f;
    }
    __syncthreads();
    Xf[(size_t)tok*320 + tid] = f16b(e*sh[4]);
    return;
  }
  int u = tid & 63, sg = tid >> 6;
  int sbase = b*64 + sg*16;
  float c[16];
  float4 acc[16];
  for (int t = 0; t < C_; ++t) {
    #pragma unroll
    for (int i = 0; i < 16; ++i) {
      int ch = chars[(sbase + i)*C_ + t];
      acc[i] = *(const float4*)(preT + ch*256 + (u << 2));
    }
    if (t > 0) {
      const float* hp = sh + ((t - 1) & 1)*(64*68) + (sg << 4);
      #pragma unroll 2
      for (int k = 0; k < 64; ++k) {
        float4 w = *(const float4*)(whhc + (k << 8) + (u << 2));
        const float* hr = hp + k*68;
        float4 h0 = *(const float4*)(hr + 0);
        float4 h1 = *(const float4*)(hr + 4);
        float4 h2 = *(const float4*)(hr + 8);
        float4 h3 = *(const float4*)(hr + 12);
        float hv[16] = {h0.x,h0.y,h0.z,h0.w, h1.x,h1.y,h1.z,h1.w,
                        h2.x,h2.y,h2.z,h2.w, h3.x,h3.y,h3.z,h3.w};
        #pragma unroll
        for (int i = 0; i < 16; ++i) {
          acc[i].x += w.x*hv[i]; acc[i].y += w.y*hv[i];
          acc[i].z += w.z*hv[i]; acc[i].w += w.w*hv[i];
        }
      }
    }
    float* hw = sh + (t & 1)*(64*68);
    #pragma unroll
    for (int i = 0; i < 16; ++i) {
      float ig = sigf(acc[i].x), fg = sigf(acc[i].y);
      float gg = tanhf_(acc[i].z), og = sigf(acc[i].w);
      float cc = (t == 0) ? (ig*gg) : (fg*c[i] + ig*gg);
      c[i] = cc;
      float hh = og*tanhf_(cc);
      hw[u*68 + (sg << 4) + i] = hh;
      if (t == C_-1) Xf[(size_t)(sbase + i)*320 + 256 + u] = f16b(hh);
    }
    __syncthreads();
  }
}

// ================= pregate GEMM: m97-style global_load_lds + src-side XOR swizzle =================
// preg layout: [dir][s][g16=0..127][n=0..63][16 floats]
__global__ void __launch_bounds__(256) k_gemm(const ushort* __restrict__ Xf,
    const ushort* __restrict__ Whf, const ushort* __restrict__ Wlf,
    const ushort* __restrict__ Whb, const ushort* __restrict__ Wlb,
    const float* __restrict__ bPf, const float* __restrict__ bPb,
    float* __restrict__ preg, int D, int t0, int TCc) {
  int dir = blockIdx.z;
  const ushort* WhD = dir ? Whb : Whf;
  const ushort* WlD = dir ? Wlb : Wlf;
  const float*  bPD = dir ? bPb : bPf;
  int mt = blockIdx.x, nt = blockIdx.y;
  int tid = threadIdx.x;

  __shared__ __align__(16) ushort As[128*64], Bh[128*64], Bl[128*64];
  int lane = tid & 63, wid = tid >> 6;
  int wm = wid >> 1, wn = wid & 1;
  int l15 = lane & 15, l4 = lane >> 4;

  // staging: LDS dest linear (gload_lds requirement), global src chunk XOR-swizzled
  const ushort *asrc[4], *bhsrc[4], *blsrc[4];
  ushort *adst[4], *bhdst[4], *bldst[4];
  #pragma unroll
  for (int c = 0; c < 4; ++c) {
    int idx = c*256 + tid;
    int row = idx >> 3, ch = idx & 7;
    int chs = ch ^ (row & 7);                 // source-side swizzle (involution)
    int r = mt*128 + row, s = r >> 6, n = r & 63;
    int ttt = dir ? (T_ - 1 - (t0 + s)) : (t0 + s);
    asrc[c]  = Xf  + ((size_t)n*T_ + ttt)*D + chs*8;
    bhsrc[c] = WhD + (size_t)(nt*128 + row)*D + chs*8;
    blsrc[c] = WlD + (size_t)(nt*128 + row)*D + chs*8;
    adst[c]  = As + idx*8; bhdst[c] = Bh + idx*8; bldst[c] = Bl + idx*8;
  }
  int sw = l15 & 7;
  int rA[4], rB[4];
  #pragma unroll
  for (int f = 0; f < 4; ++f) {
    rA[f] = (wm*64 + f*16 + l15) << 6;
    rB[f] = (wn*64 + f*16 + l15) << 6;
  }

  f32x4 acc[4][4];
  #pragma unroll
  for (int a = 0; a < 4; ++a)
    #pragma unroll
    for (int bq = 0; bq < 4; ++bq) acc[a][bq] = (f32x4){0.f,0.f,0.f,0.f};

  for (int k0 = 0; k0 < D; k0 += 64) {
    __syncthreads();
    #pragma unroll
    for (int c = 0; c < 4; ++c) {
      __builtin_amdgcn_global_load_lds(
        (const __attribute__((address_space(1))) void*)(asrc[c] + k0),
        (__attribute__((address_space(3))) void*)adst[c], 16, 0, 0);
      __builtin_amdgcn_global_load_lds(
        (const __attribute__((address_space(1))) void*)(bhsrc[c] + k0),
        (__attribute__((address_space(3))) void*)bhdst[c], 16, 0, 0);
      __builtin_amdgcn_global_load_lds(
        (const __attribute__((address_space(1))) void*)(blsrc[c] + k0),
        (__attribute__((address_space(3))) void*)bldst[c], 16, 0, 0);
    }
    asm volatile("s_waitcnt vmcnt(0)" ::: "memory");
    __syncthreads();
    #pragma unroll
    for (int ks = 0; ks < 2; ++ks) {
      int fo = (((ks << 2) + l4) ^ sw) << 3;   // swizzled 16B-chunk read
      f16x8 av[4], bhv[4], blv[4];
      #pragma unroll
      for (int mf = 0; mf < 4; ++mf)
        av[mf] = __builtin_bit_cast(f16x8, *(const short8*)(As + rA[mf] + fo));
      #pragma unroll
      for (int nf = 0; nf < 4; ++nf) {
        bhv[nf] = __builtin_bit_cast(f16x8, *(const short8*)(Bh + rB[nf] + fo));
        blv[nf] = __builtin_bit_cast(f16x8, *(const short8*)(Bl + rB[nf] + fo));
      }
      #pragma unroll
      for (int mf = 0; mf < 4; ++mf)
        #pragma unroll
        for (int nf = 0; nf < 4; ++nf) {
          acc[mf][nf] = __builtin_amdgcn_mfma_f32_16x16x32_f16(av[mf], bhv[nf], acc[mf][nf], 0,0,0);
          acc[mf][nf] = __builtin_amdgcn_mfma_f32_16x16x32_f16(av[mf], blv[nf], acc[mf][nf], 0,0,0);
        }
    }
  }
  float bias[4];
  #pragma unroll
  for (int nf = 0; nf < 4; ++nf) bias[nf] = bPD[nt*128 + wn*64 + nf*16 + l15];
  #pragma unroll
  for (int mf = 0; mf < 4; ++mf)
    #pragma unroll
    for (int nf = 0; nf < 4; ++nf) {
      int g16 = nt*8 + wn*4 + nf;
      #pragma unroll
      for (int rr = 0; rr < 4; ++rr) {
        int r = mt*128 + wm*64 + mf*16 + (l4 << 2) + rr;
        int s = r >> 6, n = r & 63;
        preg[((size_t)(dir*TCc + s)*128 + g16)*1024 + n*16 + l15] = acc[mf][nf][rr] + bias[nf];
      }
    }
}

// ================= main recurrence: 64 blocks x 4 waves, LLC-coherent, fence-free =================
__global__ void __launch_bounds__(256, 1) k_rec(const float* __restrict__ preg,
    const float* __restrict__ whhf, const float* __restrict__ whhb,
    ushort* __restrict__ XO, ushort* __restrict__ hF, float* __restrict__ cst,
    int* __restrict__ barr, int t0, int TCc, int ebase,
    int doCls, const float* __restrict__ Wc, const float* __restrict__ bc,
    float* __restrict__ outp) {
  __shared__ ushort hs[64*16];
  __shared__ float red[64][4][3];
  int bi = blockIdx.x;
  int dir = bi >> 5, ublk = bi & 31;
  const float* whh = dir ? whhb : whhf;
  int tid = threadIdx.x, w = tid >> 6, l = tid & 63;
  int l31 = l & 31, l5 = l >> 5;
  int gh = w & 1, nh = w >> 1;
  int n_ = nh*32 + l31;
  int q = l31 & 3;
  int urow = ublk*16 + gh*8 + (l31 >> 2);
  int g16b = ublk*4 + gh*2;

  // ---- Whh slice -> registers (fp16 hi/lo) ----
  f16x8 ah[32], al[32];
  {
    const float* wr = whh + ((size_t)(q*512 + urow))*512 + l5*8;
    #pragma unroll
    for (int ks = 0; ks < 32; ++ks) {
      float4 w0 = *(const float4*)(wr + ks*16);
      float4 w1 = *(const float4*)(wr + ks*16 + 4);
      float wf[8] = {w0.x,w0.y,w0.z,w0.w, w1.x,w1.y,w1.z,w1.w};
      short8 h8, l8;
      #pragma unroll
      for (int j = 0; j < 8; ++j) {
        ushort hb_, lb_; fsplit(wf[j], hb_, lb_);
        h8[j] = (short)hb_; l8[j] = (short)lb_;
      }
      ah[ks] = __builtin_bit_cast(f16x8, h8);
      al[ks] = __builtin_bit_cast(f16x8, l8);
    }
  }
  float cv[4];
  #pragma unroll
  for (int e = 0; e < 4; ++e) {
    int u = ublk*16 + gh*8 + 2*e + l5;
    cv[e] = (t0 == 0) ? 0.f : cst[(size_t)(dir*64 + n_)*512 + u];
  }
  // prologue: preg for s=0
  f32x16 accH;
  {
    const float* pb = preg + (size_t)(dir*TCc)*131072;
    #pragma unroll
    for (int e = 0; e < 4; ++e) {
      f32x4 v = *(const f32x4*)(pb + (g16b + (e>>1))*1024 + n_*16 + 8*(e&1) + 4*l5);
      accH[4*e+0]=v[0]; accH[4*e+1]=v[1]; accH[4*e+2]=v[2]; accH[4*e+3]=v[3];
    }
  }
  int* arrd = barr + dir*32;

  #pragma unroll 1
  for (int s = 0; s < TCc; ++s) {
    int t = t0 + s;
    int tt = dir ? (T_ - 1 - t) : t;
    f32x16 accL = (f32x16)(0.f);
    if (t > 0) {
      const ushort* hb = hF + (size_t)((dir<<1) | ((t-1)&1))*32768 + n_*512 + l5*8;
      f16x8 h0[8], h1[8], h2[8];
      #pragma unroll
      for (int j = 0; j < 8; ++j) LLCLD(h0[j], hb, (0+j)*32);
      #pragma unroll
      for (int j = 0; j < 8; ++j) LLCLD(h1[j], hb, (8+j)*32);
      // chunk0
      asm volatile("s_waitcnt vmcnt(8)" ::: "memory");
      __builtin_amdgcn_sched_barrier(0);
      #pragma unroll
      for (int j = 0; j < 8; ++j) LLCLD(h2[j], hb, (16+j)*32);
      #pragma unroll
      for (int j = 0; j < 8; ++j) {
        accH = __builtin_amdgcn_mfma_f32_32x32x16_f16(ah[j], h0[j], accH, 0,0,0);
        accL = __builtin_amdgcn_mfma_f32_32x32x16_f16(al[j], h0[j], accL, 0,0,0);
      }
      // chunk1
      asm volatile("s_waitcnt vmcnt(8)" ::: "memory");
      __builtin_amdgcn_sched_barrier(0);
      #pragma unroll
      for (int j = 0; j < 8; ++j) LLCLD(h0[j], hb, (24+j)*32);
      #pragma unroll
      for (int j = 0; j < 8; ++j) {
        accH = __builtin_amdgcn_mfma_f32_32x32x16_f16(ah[8+j], h1[j], accH, 0,0,0);
        accL = __builtin_amdgcn_mfma_f32_32x32x16_f16(al[8+j], h1[j], accL, 0,0,0);
      }
      // chunk2
      asm volatile("s_waitcnt vmcnt(8)" ::: "memory");
      __builtin_amdgcn_sched_barrier(0);
      #pragma unroll
      for (int j = 0; j < 8; ++j) {
        accH = __builtin_amdgcn_mfma_f32_32x32x16_f16(ah[16+j], h2[j], accH, 0,0,0);
        accL = __builtin_amdgcn_mfma_f32_32x32x16_f16(al[16+j], h2[j], accL, 0,0,0);
      }
      // chunk3
      asm volatile("s_waitcnt vmcnt(0)" ::: "memory");
      __builtin_amdgcn_sched_barrier(0);
      #pragma unroll
      for (int j = 0; j < 8; ++j) {
        accH = __builtin_amdgcn_mfma_f32_32x32x16_f16(ah[24+j], h0[j], accH, 0,0,0);
        accL = __builtin_amdgcn_mfma_f32_32x32x16_f16(al[24+j], h0[j], accL, 0,0,0);
      }
    }
    // gates
    #pragma unroll
    for (int e = 0; e < 4; ++e) {
      float ig = sigf(accH[4*e+0] + accL[4*e+0]);
      float fg = sigf(accH[4*e+1] + accL[4*e+1]);
      float gg = tanhf_(accH[4*e+2] + accL[4*e+2]);
      float og = sigf(accH[4*e+3] + accL[4*e+3]);
      float c = (t == 0) ? (ig*gg) : (fg*cv[e] + ig*gg);
      cv[e] = c;
      float h = og*tanhf_(c);
      int ul = gh*8 + 2*e + l5;
      hs[n_*16 + (ul ^ ((n_&1)<<3))] = f16b(h);
    }
    __syncthreads();
    // cooperative store of the block's 16-unit slice: hF via LLC write-through
    int n2 = tid >> 2, c2 = tid & 3;
    short4 hv = *(const short4*)&hs[n2*16 + ((c2 ^ ((n2&1)<<1)) << 2)];
    {
      ushort* hdst = hF + (size_t)((dir<<1)|(t&1))*32768 + n2*512 + ublk*16 + c2*4;
      asm volatile("global_store_dwordx2 %0, %1, off sc0 sc1" :: "v"(hdst), "v"(hv) : "memory");
    }
    asm volatile("s_waitcnt vmcnt(0)" ::: "memory");   // release: stores acked at LLC
    __syncthreads();
    int epoch = ebase + s + 1;
    if (tid == 0)
      __hip_atomic_store(&arrd[ublk], epoch, __ATOMIC_RELAXED, __HIP_MEMORY_SCOPE_AGENT);
    // off-critical-path work overlaps the spin:
    if (XO) *(short4*)(XO + (size_t)n2*262144 + (size_t)tt*1024 + dir*512 + ublk*16 + c2*4) = hv;
    if (s + 1 < TCc) {
      const float* pb = preg + (size_t)(dir*TCc + s + 1)*131072;
      #pragma unroll
      for (int e = 0; e < 4; ++e) {
        f32x4 v = *(const f32x4*)(pb + (g16b + (e>>1))*1024 + n_*16 + 8*(e&1) + 4*l5);
        accH[4*e+0]=v[0]; accH[4*e+1]=v[1]; accH[4*e+2]=v[2]; accH[4*e+3]=v[3];
      }
    }
    if (w == 0) {               // flagless direct poll of all 32 blocks of this dir
      bool done = false;
      while (!done) {
        int v = (l < 32) ? __hip_atomic_load(&arrd[l], __ATOMIC_RELAXED, __HIP_MEMORY_SCOPE_AGENT)
                         : 0x7fffffff;
        done = (__ballot(v >= epoch) == ~0ull);
      }
    }
    __syncthreads();
  }
  #pragma unroll
  for (int e = 0; e < 4; ++e)
    cst[(size_t)(dir*64 + n_)*512 + ublk*16 + gh*8 + 2*e + l5] = cv[e];

  // ---- fused classifier: block 0 waits for dir1 completion ----
  if (doCls && bi == 0) {
    int eEnd = ebase + TCc;
    if (w == 0) {
      bool done = false;
      while (!done) {
        int v = (l < 32) ? __hip_atomic_load(&barr[32 + l], __ATOMIC_RELAXED, __HIP_MEMORY_SCOPE_AGENT)
                         : 0x7fffffff;
        done = (__ballot(v >= eEnd) == ~0ull);
      }
    }
    __syncthreads();
    int n = tid >> 2, p = tid & 3;
    const ULL* f0 = (const ULL*)(hF + 32768 + n*512) + p*32;      // fwd h(T-1), phase 1
    const ULL* f1 = (const ULL*)(hF + 3*32768 + n*512) + p*32;    // bwd h(t=0),  phase 1
    float p0 = 0.f, p1 = 0.f, p2 = 0.f;
    for (int j8 = 0; j8 < 32; ++j8) {
      ULL v0 = __hip_atomic_load(f0 + j8, __ATOMIC_RELAXED, __HIP_MEMORY_SCOPE_AGENT);
      ULL v1 = __hip_atomic_load(f1 + j8, __ATOMIC_RELAXED, __HIP_MEMORY_SCOPE_AGENT);
      #pragma unroll
      for (int e = 0; e < 4; ++e) {
        int j = p*128 + j8*4 + e;
        float a  = f16f((ushort)(v0 >> (16*e)));
        float b2 = f16f((ushort)(v1 >> (16*e)));
        p0 += a*Wc[j]        + b2*Wc[512 + j];
        p1 += a*Wc[1024 + j] + b2*Wc[1536 + j];
        p2 += a*Wc[2048 + j] + b2*Wc[2560 + j];
      }
    }
    red[n][p][0] = p0; red[n][p][1] = p1; red[n][p][2] = p2;
    __syncthreads();
    if (tid < 192) {
      int nn = tid / 3, o = tid - nn*3;
      outp[nn*3 + o] = red[nn][0][o] + red[nn][1][o] + red[nn][2][o] + red[nn][3][o] + bc[o];
    }
  }
}

extern "C" void kernel_launch(void* const* d_in, const int* in_sizes, int n_in,
                              void* d_out, int out_size, void* d_ws, size_t ws_size,
                              hipStream_t stream) {
  (void)in_sizes; (void)n_in; (void)out_size;
  const int*   words  = (const int*)d_in[0];
  const int*   chars  = (const int*)d_in[1];
  const float* wl_emb = (const float*)d_in[2];
  const float* cl_emb = (const float*)d_in[3];
  const float* c_wih  = (const float*)d_in[4];
  const float* c_whh  = (const float*)d_in[5];
  const float* c_b    = (const float*)d_in[6];
  const float* WIH[6] = {
    (const float*)d_in[7],  (const float*)d_in[10],
    (const float*)d_in[13], (const float*)d_in[16],
    (const float*)d_in[13] + (size_t)2048*1024, (const float*)d_in[16] + (size_t)2048*1024 };
  const float* WHH[3][2] = {
    { (const float*)d_in[8],  (const float*)d_in[11] },
    { (const float*)d_in[14], (const float*)d_in[17] },
    { (const float*)d_in[14] + (size_t)2048*512, (const float*)d_in[17] + (size_t)2048*512 } };
  const float* BB[6] = {
    (const float*)d_in[9],  (const float*)d_in[12],
    (const float*)d_in[15], (const float*)d_in[18],
    (const float*)d_in[15] + 2048, (const float*)d_in[18] + 2048 };
  const float* Wc = (const float*)d_in[19];
  const float* bc = (const float*)d_in[20];

  // -------- workspace carve --------
  float* wsp = (float*)d_ws;
  size_t off = 0;
  auto carve = [&](size_t nf) { float* p = wsp + off; off += (nf + 63) & ~(size_t)63; return p; };
  ushort* XA = (ushort*)carve((size_t)16384*1024/2);
  ushort* XB = (ushort*)carve((size_t)16384*1024/2);
  ushort* Wh6[6]; ushort* Wl6[6];
  for (int ld = 0; ld < 6; ++ld) {
    size_t D = (ld < 2) ? 320 : 1024;
    Wh6[ld] = (ushort*)carve((size_t)2048*D/2);
    Wl6[ld] = (ushort*)carve((size_t)2048*D/2);
  }
  float* bP   = carve(6*2048);
  float* preT = carve(100*256);
  float* whhc = carve(64*256);
  ushort* hF  = (ushort*)carve((size_t)4*32768/2);
  float* cst  = carve((size_t)2*64*512);
  int* barr   = (int*)carve(64);
  size_t wsFloats = ws_size / 4;
  int TCc = 256;
  while (TCc > 16 && off + (size_t)2*TCc*64*2048 > wsFloats) TCc >>= 1;
  float* preg = carve((size_t)2*TCc*64*2048);
  if (off > wsFloats) return;   // insufficient workspace -> loud validation failure

  // -------- node 1: all weight prep (+ barrier-slot zeroing) --------
  PrepArgs pa;
  pa.cl_emb = cl_emb; pa.c_wih = c_wih; pa.c_b = c_b; pa.c_whh = c_whh;
  for (int ld = 0; ld < 6; ++ld) { pa.wih[ld] = WIH[ld]; pa.bb[ld] = BB[ld];
                                   pa.Wh[ld] = Wh6[ld]; pa.Wl[ld] = Wl6[ld]; }
  pa.preT = preT; pa.whhc = whhc; pa.bP = bP; pa.barr = barr;
  k_prep<<<9684, 256, 0, stream>>>(pa);

  // -------- node 2: word embedding + char LSTM --------
  k_wordchar<<<16640, 256, 0, stream>>>(words, chars, wl_emb, preT, whhc, XA);

  // -------- 3 stacked BiLSTM layers --------
  for (int l = 0; l < 3; ++l) {
    const ushort* Xin = (l == 1) ? XB : XA;
    ushort* Xout = (l == 0) ? XB : ((l == 1) ? XA : nullptr);
    int D = l ? 1024 : 320;
    for (int t0 = 0; t0 < T_; t0 += TCc) {
      k_gemm<<<dim3(TCc/2, 16, 2), 256, 0, stream>>>(Xin,
          Wh6[2*l], Wl6[2*l], Wh6[2*l+1], Wl6[2*l+1],
          bP + (2*l)*2048, bP + (2*l+1)*2048, preg, D, t0, TCc);
      int doCls = (l == 2 && t0 + TCc == T_) ? 1 : 0;
      k_rec<<<64, 256, 0, stream>>>(preg, WHH[l][0], WHH[l][1], Xout, hF, cst,
                                    barr, t0, TCc, l*T_ + t0, doCls, Wc, bc, (float*)d_out);
    }
  }
}

// Round 8
// 5938.198 us; speedup vs baseline: 10.0592x; 1.0644x over previous
//
#include <hip/hip_runtime.h>
#include <math.h>

#define T_   256
#define C_   16

typedef float    f32x4  __attribute__((ext_vector_type(4)));
typedef float    f32x16 __attribute__((ext_vector_type(16)));
typedef _Float16 f16x8  __attribute__((ext_vector_type(8)));
typedef short    short8 __attribute__((ext_vector_type(8)));
typedef unsigned long long ULL;

__device__ __forceinline__ float sigf(float x)  { return 1.0f/(1.0f + __expf(-x)); }
__device__ __forceinline__ float tanhf_(float x){ return 1.0f - 2.0f/(1.0f + __expf(2.0f*x)); }

__device__ __forceinline__ ushort f16b(float w) {
  _Float16 h = (_Float16)w; return __builtin_bit_cast(ushort, h);
}
__device__ __forceinline__ float f16f(ushort b) {
  return (float)__builtin_bit_cast(_Float16, b);
}

// LLC-coherent 16B load (bypass L1/L2 both ways; no fences needed)
#define LLCLD(dst, base, OFF) \
  asm volatile("global_load_dwordx4 %0, %1, off offset:%c2 sc0 sc1" \
               : "=v"(dst) : "v"(base), "n"(OFF) : "memory")

// ================= k_prep: ALL weight prep in one node =================
struct PrepArgs {
  const float *cl_emb, *c_wih, *c_b, *c_whh;
  const float *wih[6];
  const float *bb[6];
  ushort *Wh[6];
  float *preT, *whhc, *bP;
  int *barr;
};

__global__ void __launch_bounds__(256) k_prep(PrepArgs A) {
  __shared__ float e[64];
  int b = blockIdx.x, tid = threadIdx.x;
  if (b == 0 && tid < 64) A.barr[tid] = 0;   // zero barrier slots every launch
  if (b < 100) {
    if (tid < 64) e[tid] = A.cl_emb[b*64 + tid];
    __syncthreads();
    float ss = 0.f;
    #pragma unroll 8
    for (int k = 0; k < 64; ++k) ss += e[k]*e[k];
    float nn = sqrtf(ss);
    float scl = (nn > 1.0f) ? 1.0f/nn : 1.0f;
    int u = tid >> 2, q = tid & 3;
    const float* wrow = A.c_wih + (q*64 + u)*64;
    float acc = 0.f;
    #pragma unroll 8
    for (int k = 0; k < 64; ++k) acc += e[k]*wrow[k];
    A.preT[b*256 + tid] = A.c_b[q*64 + u] + scl*acc;
  } else if (b < 164) {
    int i = (b - 100)*256 + tid;
    int k = i >> 8, rem = i & 255, u = rem >> 2, q = rem & 3;
    A.whhc[i] = A.c_whh[(q*64 + u)*64 + k];
  } else if (b < 212) {
    int i = (b - 164)*256 + tid;
    int ld = i >> 11, j = i & 2047, u = j >> 2, q = j & 3;
    A.bP[i] = A.bb[ld][q*512 + u];
  } else {
    int idx = b - 212;
    int ld, off, D;
    if (idx < 1280) { ld = idx / 640; off = idx - ld*640; D = 320; }
    else { idx -= 1280; ld = 2 + (idx >> 11); off = idx & 2047; D = 1024; }
    int i4 = off*256 + tid;
    int D4 = D >> 2;
    int g4 = i4 / D4, k4 = i4 - g4*D4;
    int u = g4 >> 2, q = g4 & 3;
    float4 v = *(const float4*)(A.wih[ld] + (size_t)(q*512 + u)*D + (k4 << 2));
    ushort4 hh;
    hh.x = f16b(v.x); hh.y = f16b(v.y); hh.z = f16b(v.z); hh.w = f16b(v.w);
    *(ushort4*)(A.Wh[ld] + (size_t)g4*D + (k4 << 2)) = hh;
  }
}

// ================= k_wordchar: word emb + char LSTM =================
__global__ void __launch_bounds__(256) k_wordchar(const int* __restrict__ words,
    const int* __restrict__ chars, const float* __restrict__ wl_emb,
    const float* __restrict__ preT, const float* __restrict__ whhc,
    ushort* __restrict__ Xf) {
  __shared__ float sh[2*64*68];
  int b = blockIdx.x, tid = threadIdx.x;
  if (b >= 256) {
    int tok = b - 256;
    int row = words[tok];
    float e = wl_emb[(size_t)row*256 + tid];
    float ss = e*e;
    #pragma unroll
    for (int o = 32; o; o >>= 1) ss += __shfl_xor(ss, o, 64);
    int lane = tid & 63, wv = tid >> 6;
    if (lane == 0) sh[wv] = ss;
    __syncthreads();
    if (tid == 0) {
      float s2 = sh[0] + sh[1] + sh[2] + sh[3];
      float nn = sqrtf(s2);
      sh[4] = (nn > 1.0f) ? 1.0f/nn : 1.0f;
    }
    __syncthreads();
    Xf[(size_t)tok*320 + tid] = f16b(e*sh[4]);
    return;
  }
  int u = tid & 63, sg = tid >> 6;
  int sbase = b*64 + sg*16;
  float c[16];
  float4 acc[16];
  for (int t = 0; t < C_; ++t) {
    #pragma unroll
    for (int i = 0; i < 16; ++i) {
      int ch = chars[(sbase + i)*C_ + t];
      acc[i] = *(const float4*)(preT + ch*256 + (u << 2));
    }
    if (t > 0) {
      const float* hp = sh + ((t - 1) & 1)*(64*68) + (sg << 4);
      #pragma unroll 2
      for (int k = 0; k < 64; ++k) {
        float4 w = *(const float4*)(whhc + (k << 8) + (u << 2));
        const float* hr = hp + k*68;
        float4 h0 = *(const float4*)(hr + 0);
        float4 h1 = *(const float4*)(hr + 4);
        float4 h2 = *(const float4*)(hr + 8);
        float4 h3 = *(const float4*)(hr + 12);
        float hv[16] = {h0.x,h0.y,h0.z,h0.w, h1.x,h1.y,h1.z,h1.w,
                        h2.x,h2.y,h2.z,h2.w, h3.x,h3.y,h3.z,h3.w};
        #pragma unroll
        for (int i = 0; i < 16; ++i) {
          acc[i].x += w.x*hv[i]; acc[i].y += w.y*hv[i];
          acc[i].z += w.z*hv[i]; acc[i].w += w.w*hv[i];
        }
      }
    }
    float* hw = sh + (t & 1)*(64*68);
    #pragma unroll
    for (int i = 0; i < 16; ++i) {
      float ig = sigf(acc[i].x), fg = sigf(acc[i].y);
      float gg = tanhf_(acc[i].z), og = sigf(acc[i].w);
      float cc = (t == 0) ? (ig*gg) : (fg*c[i] + ig*gg);
      c[i] = cc;
      float hh = og*tanhf_(cc);
      hw[u*68 + (sg << 4) + i] = hh;
      if (t == C_-1) Xf[(size_t)(sbase + i)*320 + 256 + u] = f16b(hh);
    }
    __syncthreads();
  }
}

// ================= pregate GEMM: global_load_lds + src-side XOR swizzle, fp16 W =================
// preg layout: [dir][s][g16=0..127][n=0..63][16 floats]
__global__ void __launch_bounds__(256) k_gemm(const ushort* __restrict__ Xf,
    const ushort* __restrict__ Whf, const ushort* __restrict__ Whb,
    const float* __restrict__ bPf, const float* __restrict__ bPb,
    float* __restrict__ preg, int D, int t0, int TCc) {
  int dir = blockIdx.z;
  const ushort* WhD = dir ? Whb : Whf;
  const float*  bPD = dir ? bPb : bPf;
  int mt = blockIdx.x, nt = blockIdx.y;
  int tid = threadIdx.x;

  __shared__ __align__(16) ushort As[128*64], Bh[128*64];
  int lane = tid & 63, wid = tid >> 6;
  int wm = wid >> 1, wn = wid & 1;
  int l15 = lane & 15, l4 = lane >> 4;

  // staging: LDS dest linear (gload_lds requirement), global src chunk XOR-swizzled
  const ushort *asrc[4], *bhsrc[4];
  ushort *adst[4], *bhdst[4];
  #pragma unroll
  for (int c = 0; c < 4; ++c) {
    int idx = c*256 + tid;
    int row = idx >> 3, ch = idx & 7;
    int chs = ch ^ (row & 7);                 // source-side swizzle (involution)
    int r = mt*128 + row, s = r >> 6, n = r & 63;
    int ttt = dir ? (T_ - 1 - (t0 + s)) : (t0 + s);
    asrc[c]  = Xf  + ((size_t)n*T_ + ttt)*D + chs*8;
    bhsrc[c] = WhD + (size_t)(nt*128 + row)*D + chs*8;
    adst[c]  = As + idx*8; bhdst[c] = Bh + idx*8;
  }
  int sw = l15 & 7;
  int rA[4], rB[4];
  #pragma unroll
  for (int f = 0; f < 4; ++f) {
    rA[f] = (wm*64 + f*16 + l15) << 6;
    rB[f] = (wn*64 + f*16 + l15) << 6;
  }

  f32x4 acc[4][4];
  #pragma unroll
  for (int a = 0; a < 4; ++a)
    #pragma unroll
    for (int bq = 0; bq < 4; ++bq) acc[a][bq] = (f32x4){0.f,0.f,0.f,0.f};

  for (int k0 = 0; k0 < D; k0 += 64) {
    __syncthreads();
    #pragma unroll
    for (int c = 0; c < 4; ++c) {
      __builtin_amdgcn_global_load_lds(
        (const __attribute__((address_space(1))) void*)(asrc[c] + k0),
        (__attribute__((address_space(3))) void*)adst[c], 16, 0, 0);
      __builtin_amdgcn_global_load_lds(
        (const __attribute__((address_space(1))) void*)(bhsrc[c] + k0),
        (__attribute__((address_space(3))) void*)bhdst[c], 16, 0, 0);
    }
    asm volatile("s_waitcnt vmcnt(0)" ::: "memory");
    __syncthreads();
    #pragma unroll
    for (int ks = 0; ks < 2; ++ks) {
      int fo = (((ks << 2) + l4) ^ sw) << 3;   // swizzled 16B-chunk read
      f16x8 av[4], bhv[4];
      #pragma unroll
      for (int mf = 0; mf < 4; ++mf)
        av[mf] = __builtin_bit_cast(f16x8, *(const short8*)(As + rA[mf] + fo));
      #pragma unroll
      for (int nf = 0; nf < 4; ++nf)
        bhv[nf] = __builtin_bit_cast(f16x8, *(const short8*)(Bh + rB[nf] + fo));
      #pragma unroll
      for (int mf = 0; mf < 4; ++mf)
        #pragma unroll
        for (int nf = 0; nf < 4; ++nf)
          acc[mf][nf] = __builtin_amdgcn_mfma_f32_16x16x32_f16(av[mf], bhv[nf], acc[mf][nf], 0,0,0);
    }
  }
  float bias[4];
  #pragma unroll
  for (int nf = 0; nf < 4; ++nf) bias[nf] = bPD[nt*128 + wn*64 + nf*16 + l15];
  #pragma unroll
  for (int mf = 0; mf < 4; ++mf)
    #pragma unroll
    for (int nf = 0; nf < 4; ++nf) {
      int g16 = nt*8 + wn*4 + nf;
      #pragma unroll
      for (int rr = 0; rr < 4; ++rr) {
        int r = mt*128 + wm*64 + mf*16 + (l4 << 2) + rr;
        int s = r >> 6, n = r & 63;
        preg[((size_t)(dir*TCc + s)*128 + g16)*1024 + n*16 + l15] = acc[mf][nf][rr] + bias[nf];
      }
    }
}

// ================= main recurrence: 64 blocks x 4 waves, LLC-coherent, fence-free =================
__global__ void __launch_bounds__(256, 1) k_rec(const float* __restrict__ preg,
    const float* __restrict__ whhf, const float* __restrict__ whhb,
    ushort* __restrict__ XO, ushort* __restrict__ hF, float* __restrict__ cst,
    int* __restrict__ barr, int t0, int TCc, int ebase,
    int doCls, const float* __restrict__ Wc, const float* __restrict__ bc,
    float* __restrict__ outp) {
  __shared__ ushort hs[64*16];
  __shared__ float red[64][4][3];
  int bi = blockIdx.x;
  int dir = bi >> 5, ublk = bi & 31;
  const float* whh = dir ? whhb : whhf;
  int tid = threadIdx.x, w = tid >> 6, l = tid & 63;
  int l31 = l & 31, l5 = l >> 5;
  int gh = w & 1, nh = w >> 1;
  int n_ = nh*32 + l31;
  int q = l31 & 3;
  int urow = ublk*16 + gh*8 + (l31 >> 2);
  int g16b = ublk*4 + gh*2;

  // ---- Whh slice -> registers (single fp16) ----
  f16x8 ah[32];
  {
    const float* wr = whh + ((size_t)(q*512 + urow))*512 + l5*8;
    #pragma unroll
    for (int ks = 0; ks < 32; ++ks) {
      float4 w0 = *(const float4*)(wr + ks*16);
      float4 w1 = *(const float4*)(wr + ks*16 + 4);
      float wf[8] = {w0.x,w0.y,w0.z,w0.w, w1.x,w1.y,w1.z,w1.w};
      short8 h8;
      #pragma unroll
      for (int j = 0; j < 8; ++j) h8[j] = (short)f16b(wf[j]);
      ah[ks] = __builtin_bit_cast(f16x8, h8);
    }
  }
  float cv[4];
  #pragma unroll
  for (int e = 0; e < 4; ++e) {
    int u = ublk*16 + gh*8 + 2*e + l5;
    cv[e] = (t0 == 0) ? 0.f : cst[(size_t)(dir*64 + n_)*512 + u];
  }
  // prologue: preg for s=0
  f32x16 accA;
  {
    const float* pb = preg + (size_t)(dir*TCc)*131072;
    #pragma unroll
    for (int e = 0; e < 4; ++e) {
      f32x4 v = *(const f32x4*)(pb + (g16b + (e>>1))*1024 + n_*16 + 8*(e&1) + 4*l5);
      accA[4*e+0]=v[0]; accA[4*e+1]=v[1]; accA[4*e+2]=v[2]; accA[4*e+3]=v[3];
    }
  }
  int* arrd = barr + dir*32;

  #pragma unroll 1
  for (int s = 0; s < TCc; ++s) {
    int t = t0 + s;
    int tt = dir ? (T_ - 1 - t) : t;
    f32x16 accB = (f32x16)(0.f);
    if (t > 0) {
      const ushort* hb = hF + (size_t)((dir<<1) | ((t-1)&1))*32768 + n_*512 + l5*8;
      f16x8 h0[8], h1[8], h2[8];
      #pragma unroll
      for (int j = 0; j < 8; ++j) LLCLD(h0[j], hb, (0+j)*32);
      #pragma unroll
      for (int j = 0; j < 8; ++j) LLCLD(h1[j], hb, (8+j)*32);
      // chunk0 (ks 0..7 -> accA)
      asm volatile("s_waitcnt vmcnt(8)" ::: "memory");
      __builtin_amdgcn_sched_barrier(0);
      #pragma unroll
      for (int j = 0; j < 8; ++j) LLCLD(h2[j], hb, (16+j)*32);
      #pragma unroll
      for (int j = 0; j < 8; ++j)
        accA = __builtin_amdgcn_mfma_f32_32x32x16_f16(ah[j], h0[j], accA, 0,0,0);
      // chunk1 (ks 8..15 -> accA)
      asm volatile("s_waitcnt vmcnt(8)" ::: "memory");
      __builtin_amdgcn_sched_barrier(0);
      #pragma unroll
      for (int j = 0; j < 8; ++j) LLCLD(h0[j], hb, (24+j)*32);
      #pragma unroll
      for (int j = 0; j < 8; ++j)
        accA = __builtin_amdgcn_mfma_f32_32x32x16_f16(ah[8+j], h1[j], accA, 0,0,0);
      // chunk2 (ks 16..23 -> accB)
      asm volatile("s_waitcnt vmcnt(8)" ::: "memory");
      __builtin_amdgcn_sched_barrier(0);
      #pragma unroll
      for (int j = 0; j < 8; ++j)
        accB = __builtin_amdgcn_mfma_f32_32x32x16_f16(ah[16+j], h2[j], accB, 0,0,0);
      // chunk3 (ks 24..31 -> accB)
      asm volatile("s_waitcnt vmcnt(0)" ::: "memory");
      __builtin_amdgcn_sched_barrier(0);
      #pragma unroll
      for (int j = 0; j < 8; ++j)
        accB = __builtin_amdgcn_mfma_f32_32x32x16_f16(ah[24+j], h0[j], accB, 0,0,0);
    }
    // gates
    #pragma unroll
    for (int e = 0; e < 4; ++e) {
      float ig = sigf(accA[4*e+0] + accB[4*e+0]);
      float fg = sigf(accA[4*e+1] + accB[4*e+1]);
      float gg = tanhf_(accA[4*e+2] + accB[4*e+2]);
      float og = sigf(accA[4*e+3] + accB[4*e+3]);
      float c = (t == 0) ? (ig*gg) : (fg*cv[e] + ig*gg);
      cv[e] = c;
      float h = og*tanhf_(c);
      int ul = gh*8 + 2*e + l5;
      hs[n_*16 + (ul ^ ((n_&1)<<3))] = f16b(h);
    }
    __syncthreads();
    // cooperative store of the block's 16-unit slice: hF via LLC write-through
    int n2 = tid >> 2, c2 = tid & 3;
    short4 hv = *(const short4*)&hs[n2*16 + ((c2 ^ ((n2&1)<<1)) << 2)];
    {
      ushort* hdst = hF + (size_t)((dir<<1)|(t&1))*32768 + n2*512 + ublk*16 + c2*4;
      asm volatile("global_store_dwordx2 %0, %1, off sc0 sc1" :: "v"(hdst), "v"(hv) : "memory");
    }
    asm volatile("s_waitcnt vmcnt(0)" ::: "memory");   // release: stores acked at LLC
    __syncthreads();
    int epoch = ebase + s + 1;
    if (tid == 0)
      __hip_atomic_store(&arrd[ublk], epoch, __ATOMIC_RELAXED, __HIP_MEMORY_SCOPE_AGENT);
    // off-critical-path work overlaps the spin:
    if (XO) *(short4*)(XO + (size_t)n2*262144 + (size_t)tt*1024 + dir*512 + ublk*16 + c2*4) = hv;
    if (s + 1 < TCc) {
      const float* pb = preg + (size_t)(dir*TCc + s + 1)*131072;
      #pragma unroll
      for (int e = 0; e < 4; ++e) {
        f32x4 v = *(const f32x4*)(pb + (g16b + (e>>1))*1024 + n_*16 + 8*(e&1) + 4*l5);
        accA[4*e+0]=v[0]; accA[4*e+1]=v[1]; accA[4*e+2]=v[2]; accA[4*e+3]=v[3];
      }
    }
    if (w == 0) {               // flagless direct poll of all 32 blocks of this dir
      bool done = false;
      while (!done) {
        int v = (l < 32) ? __hip_atomic_load(&arrd[l], __ATOMIC_RELAXED, __HIP_MEMORY_SCOPE_AGENT)
                         : 0x7fffffff;
        done = (__ballot(v >= epoch) == ~0ull);
      }
    }
    __syncthreads();
  }
  #pragma unroll
  for (int e = 0; e < 4; ++e)
    cst[(size_t)(dir*64 + n_)*512 + ublk*16 + gh*8 + 2*e + l5] = cv[e];

  // ---- fused classifier: block 0 waits for dir1 completion ----
  if (doCls && bi == 0) {
    int eEnd = ebase + TCc;
    if (w == 0) {
      bool done = false;
      while (!done) {
        int v = (l < 32) ? __hip_atomic_load(&barr[32 + l], __ATOMIC_RELAXED, __HIP_MEMORY_SCOPE_AGENT)
                         : 0x7fffffff;
        done = (__ballot(v >= eEnd) == ~0ull);
      }
    }
    __syncthreads();
    int n = tid >> 2, p = tid & 3;
    const ULL* f0 = (const ULL*)(hF + 32768 + n*512) + p*32;      // fwd h(T-1), phase 1
    const ULL* f1 = (const ULL*)(hF + 3*32768 + n*512) + p*32;    // bwd h(t=0),  phase 1
    float p0 = 0.f, p1 = 0.f, p2 = 0.f;
    for (int j8 = 0; j8 < 32; ++j8) {
      ULL v0 = __hip_atomic_load(f0 + j8, __ATOMIC_RELAXED, __HIP_MEMORY_SCOPE_AGENT);
      ULL v1 = __hip_atomic_load(f1 + j8, __ATOMIC_RELAXED, __HIP_MEMORY_SCOPE_AGENT);
      #pragma unroll
      for (int e = 0; e < 4; ++e) {
        int j = p*128 + j8*4 + e;
        float a  = f16f((ushort)(v0 >> (16*e)));
        float b2 = f16f((ushort)(v1 >> (16*e)));
        p0 += a*Wc[j]        + b2*Wc[512 + j];
        p1 += a*Wc[1024 + j] + b2*Wc[1536 + j];
        p2 += a*Wc[2048 + j] + b2*Wc[2560 + j];
      }
    }
    red[n][p][0] = p0; red[n][p][1] = p1; red[n][p][2] = p2;
    __syncthreads();
    if (tid < 192) {
      int nn = tid / 3, o = tid - nn*3;
      outp[nn*3 + o] = red[nn][0][o] + red[nn][1][o] + red[nn][2][o] + red[nn][3][o] + bc[o];
    }
  }
}

extern "C" void kernel_launch(void* const* d_in, const int* in_sizes, int n_in,
                              void* d_out, int out_size, void* d_ws, size_t ws_size,
                              hipStream_t stream) {
  (void)in_sizes; (void)n_in; (void)out_size;
  const int*   words  = (const int*)d_in[0];
  const int*   chars  = (const int*)d_in[1];
  const float* wl_emb = (const float*)d_in[2];
  const float* cl_emb = (const float*)d_in[3];
  const float* c_wih  = (const float*)d_in[4];
  const float* c_whh  = (const float*)d_in[5];
  const float* c_b    = (const float*)d_in[6];
  const float* WIH[6] = {
    (const float*)d_in[7],  (const float*)d_in[10],
    (const float*)d_in[13], (const float*)d_in[16],
    (const float*)d_in[13] + (size_t)2048*1024, (const float*)d_in[16] + (size_t)2048*1024 };
  const float* WHH[3][2] = {
    { (const float*)d_in[8],  (const float*)d_in[11] },
    { (const float*)d_in[14], (const float*)d_in[17] },
    { (const float*)d_in[14] + (size_t)2048*512, (const float*)d_in[17] + (size_t)2048*512 } };
  const float* BB[6] = {
    (const float*)d_in[9],  (const float*)d_in[12],
    (const float*)d_in[15], (const float*)d_in[18],
    (const float*)d_in[15] + 2048, (const float*)d_in[18] + 2048 };
  const float* Wc = (const float*)d_in[19];
  const float* bc = (const float*)d_in[20];

  // -------- workspace carve --------
  float* wsp = (float*)d_ws;
  size_t off = 0;
  auto carve = [&](size_t nf) { float* p = wsp + off; off += (nf + 63) & ~(size_t)63; return p; };
  ushort* XA = (ushort*)carve((size_t)16384*1024/2);
  ushort* XB = (ushort*)carve((size_t)16384*1024/2);
  ushort* Wh6[6];
  for (int ld = 0; ld < 6; ++ld) {
    size_t D = (ld < 2) ? 320 : 1024;
    Wh6[ld] = (ushort*)carve((size_t)2048*D/2);
  }
  float* bP   = carve(6*2048);
  float* preT = carve(100*256);
  float* whhc = carve(64*256);
  ushort* hF  = (ushort*)carve((size_t)4*32768/2);
  float* cst  = carve((size_t)2*64*512);
  int* barr   = (int*)carve(64);
  size_t wsFloats = ws_size / 4;
  int TCc = 256;
  while (TCc > 16 && off + (size_t)2*TCc*64*2048 > wsFloats) TCc >>= 1;
  float* preg = carve((size_t)2*TCc*64*2048);
  if (off > wsFloats) return;   // insufficient workspace -> loud validation failure

  // -------- node 1: all weight prep (+ barrier-slot zeroing) --------
  PrepArgs pa;
  pa.cl_emb = cl_emb; pa.c_wih = c_wih; pa.c_b = c_b; pa.c_whh = c_whh;
  for (int ld = 0; ld < 6; ++ld) { pa.wih[ld] = WIH[ld]; pa.bb[ld] = BB[ld];
                                   pa.Wh[ld] = Wh6[ld]; }
  pa.preT = preT; pa.whhc = whhc; pa.bP = bP; pa.barr = barr;
  k_prep<<<9684, 256, 0, stream>>>(pa);

  // -------- node 2: word embedding + char LSTM --------
  k_wordchar<<<16640, 256, 0, stream>>>(words, chars, wl_emb, preT, whhc, XA);

  // -------- 3 stacked BiLSTM layers --------
  for (int l = 0; l < 3; ++l) {
    const ushort* Xin = (l == 1) ? XB : XA;
    ushort* Xout = (l == 0) ? XB : ((l == 1) ? XA : nullptr);
    int D = l ? 1024 : 320;
    for (int t0 = 0; t0 < T_; t0 += TCc) {
      k_gemm<<<dim3(TCc/2, 16, 2), 256, 0, stream>>>(Xin,
          Wh6[2*l], Wh6[2*l+1],
          bP + (2*l)*2048, bP + (2*l+1)*2048, preg, D, t0, TCc);
      int doCls = (l == 2 && t0 + TCc == T_) ? 1 : 0;
      k_rec<<<64, 256, 0, stream>>>(preg, WHH[l][0], WHH[l][1], Xout, hF, cst,
                                    barr, t0, TCc, l*T_ + t0, doCls, Wc, bc, (float*)d_out);
    }
  }
}